// Round 6
// baseline (258.401 us; speedup 1.0000x reference)
//
#include <hip/hip_runtime.h>

// ---------------------------------------------------------------------------
// SelfMultiHeadAttn: x[B,S,H] -> LN(x + OutProj(SDPA(RoPE(q), RoPE(k/|k|), v)))
// B=2 S=2048 H=1024 R=16 heads, K=64 head dim. fp32 in/out.
// R6: attn K/V LDS double-buffer (prefetch next tile during compute),
//     out-proj split-K=2 (+LN merges partials), fused rope+vtrans prep.
//     Static-max softmax, XOR-swizzled LDS, global_load_lds(16B) staging.
// ---------------------------------------------------------------------------

#define B_   2
#define S_   2048
#define H_   1024
#define R_   16
#define BS_  (B_*S_)     // 4096 rows
#define NQKV 3072        // R*K*3
#define LOG2E 1.44269504088896f

typedef float    floatx4 __attribute__((ext_vector_type(4)));
typedef _Float16 half8   __attribute__((ext_vector_type(8)));
typedef _Float16 half4   __attribute__((ext_vector_type(4)));
typedef __fp16   fp16x2  __attribute__((ext_vector_type(2)));  // cvt_pkrtz ret

#if __has_builtin(__builtin_amdgcn_exp2f)
#define EXP2(x) __builtin_amdgcn_exp2f(x)
#else
#define EXP2(x) exp2f(x)
#endif

// async global -> LDS, 16 B per lane (lds dest = wave-uniform base + lane*16)
__device__ __forceinline__ void gl_lds16(const _Float16* g, _Float16* l) {
    __builtin_amdgcn_global_load_lds(
        (const __attribute__((address_space(1))) unsigned int*)g,
        (__attribute__((address_space(3))) unsigned int*)l, 16, 0, 0);
}

// ---------------- cast fp32 -> fp16 (vectorized, n % 1024 == 0) ------------
__global__ __launch_bounds__(256) void cast_f16_kernel(
    const float* __restrict__ in, _Float16* __restrict__ out, int n)
{
    int i = (blockIdx.x * 256 + threadIdx.x) * 4;
    if (i >= n) return;
    float4 v = *(const float4*)(in + i);
    half4 h;
    h.x = (_Float16)v.x; h.y = (_Float16)v.y; h.z = (_Float16)v.z; h.w = (_Float16)v.w;
    *(half4*)(out + i) = h;
}

// --------- transpose + cast: in[rows][cols] f32 -> out[cols][rows] f16 -----
__global__ __launch_bounds__(256) void transpose_cast_f16(
    const float* __restrict__ in, _Float16* __restrict__ out, int rows, int cols)
{
    __shared__ float tile[32][33];
    int bx = blockIdx.x * 32;
    int by = blockIdx.y * 32;
    int tx = threadIdx.x & 31, ty = threadIdx.x >> 5;
#pragma unroll
    for (int i = 0; i < 32; i += 8)
        tile[ty + i][tx] = in[(size_t)(by + ty + i) * cols + bx + tx];
    __syncthreads();
#pragma unroll
    for (int i = 0; i < 32; i += 8)
        out[(size_t)(bx + ty + i) * rows + by + tx] = (_Float16)tile[tx][ty + i];
}

// ------------- f16 MFMA GEMM with split-K:  Cz = A @ Bt^T (+bias+resid) ----
// z = blockIdx.z selects K-range [z*kPerSplit, (z+1)*kPerSplit) and output
// buffer C + z*M*N. bias/resid applied only in the z==0 partial.
//   A: lane holds A[m=lane&15][k = 8*(lane>>4) + j]
//   B: lane holds B[k = 8*(lane>>4) + j][n=lane&15]   (reads Bt[n][k] contig)
//   D: reg r holds D[row = 4*(lane>>4) + r][col = lane&15]
__global__ __launch_bounds__(256) void gemm_f16_mfma(
    const _Float16* __restrict__ A, const _Float16* __restrict__ Bt,
    const float* __restrict__ bias, const float* __restrict__ resid,
    float* __restrict__ C, int M, int N, int Kd, int kPerSplit)
{
    __shared__ _Float16 Als[128 * 32];
    __shared__ _Float16 Bls[128 * 32];
    int tid  = threadIdx.x;
    int lane = tid & 63, w = tid >> 6;
    int wr = w >> 1, wc = w & 1;
    int fr = lane & 15, fq = lane >> 4;
    int m0 = blockIdx.y * 128, n0 = blockIdx.x * 128;
    int z  = blockIdx.z;
    int kBeg = z * kPerSplit, kEnd = kBeg + kPerSplit;
    float* Cz = C + (size_t)z * M * N;

    floatx4 acc[4][4] = {};

    const _Float16* ga[2]; const _Float16* gb[2];
    _Float16 *la[2], *lb[2];
#pragma unroll
    for (int i2 = 0; i2 < 2; ++i2) {
        int ch = 2 * w + i2;
        int row = ch * 16 + (lane >> 2), col = (lane & 3) * 8;
        ga[i2] = A  + (size_t)(m0 + row) * Kd + col;
        gb[i2] = Bt + (size_t)(n0 + row) * Kd + col;
        la[i2] = Als + ch * 512;
        lb[i2] = Bls + ch * 512;
    }

    for (int k0 = kBeg; k0 < kEnd; k0 += 32) {
        __syncthreads();
#pragma unroll
        for (int i2 = 0; i2 < 2; ++i2) {
            gl_lds16(ga[i2] + k0, la[i2]);
            gl_lds16(gb[i2] + k0, lb[i2]);
        }
        __syncthreads();
        half8 af[4], bf[4];
#pragma unroll
        for (int i = 0; i < 4; ++i)
            af[i] = *(const half8*)(Als + (wr * 64 + i * 16 + fr) * 32 + fq * 8);
#pragma unroll
        for (int j = 0; j < 4; ++j)
            bf[j] = *(const half8*)(Bls + (wc * 64 + j * 16 + fr) * 32 + fq * 8);
#pragma unroll
        for (int i = 0; i < 4; ++i)
#pragma unroll
            for (int j = 0; j < 4; ++j)
                acc[i][j] = __builtin_amdgcn_mfma_f32_16x16x32_f16(
                    af[i], bf[j], acc[i][j], 0, 0, 0);
    }

#pragma unroll
    for (int i = 0; i < 4; ++i)
#pragma unroll
        for (int j = 0; j < 4; ++j)
#pragma unroll
            for (int r2 = 0; r2 < 4; ++r2) {
                int row = m0 + wr * 64 + i * 16 + fq * 4 + r2;
                int col = n0 + wc * 64 + j * 16 + fr;
                float v = acc[i][j][r2];
                if (z == 0) {
                    v += bias[col];
                    if (resid) v += resid[(size_t)row * N + col];
                }
                Cz[(size_t)row * N + col] = v;
            }
}

// ------- fused prep: k-normalize + RoPE -> qt/kt f16; V -> vt2 image -------
// grid (head 32, s-tile 32), block 256 = 4 waves.
// vt2[head][tau][d][P]: position P of row d holds V[key_of(P,d)][d] with
// op=P>>3, ol=op^(d&7): key_of = 32*(ol>>2)+16*((P>>2)&1)+4*(ol&3)+(P&3)
// (bakes PV keymap + bank XOR swizzle). q~ pre-scaled by LOG2E.
__global__ __launch_bounds__(256) void prep_kernel(
    const float* __restrict__ qkv, const float* __restrict__ pos,
    _Float16* __restrict__ qt, _Float16* __restrict__ kt,
    _Float16* __restrict__ vt2)
{
    __shared__ float tile[64][65];
    int head = blockIdx.x, tau = blockIdx.y;
    int s0 = tau * 64;
    int b = head >> 4, rh = head & 15;
    int lane = threadIdx.x & 63, w = threadIdx.x >> 6;

    // ---- V slice -> LDS ----
#pragma unroll
    for (int si = w; si < 64; si += 4)
        tile[si][lane] = qkv[(size_t)(b * S_ + s0 + si) * NQKV + rh * 192 + 128 + lane];
    __syncthreads();
    {
        int P = lane;
        int op = P >> 3;
        int hi = (P >> 2) & 1, lo = P & 3;
#pragma unroll
        for (int d = w; d < 64; d += 4) {
            int ol = op ^ (d & 7);
            int key = 32 * (ol >> 2) + 16 * hi + 4 * (ol & 3) + lo;
            vt2[(((size_t)head * 32 + tau) * 64 + d) * 64 + P] = (_Float16)tile[key][d];
        }
    }

    // ---- RoPE + k-norm: wave w handles rows s0 + w*16 + i ----
    for (int i = 0; i < 16; ++i) {
        int s = s0 + w * 16 + i;
        int bs = b * S_ + s;
        const float* base = qkv + (size_t)bs * NQKV + rh * 192;
        float qv = base[lane];
        float kv = base[64 + lane];

        float ss = kv * kv;
#pragma unroll
        for (int off = 32; off > 0; off >>= 1) ss += __shfl_xor(ss, off);
        kv *= rsqrtf(ss);

        int j = lane & 31;
        float sn = pos[(size_t)bs * 64 + j];
        float cs = pos[(size_t)bs * 64 + 32 + j];
        float qp = __shfl_xor(qv, 32);
        float kp = __shfl_xor(kv, 32);
        float qo, ko;
        if (lane < 32) { qo = qv * cs - qp * sn; ko = kv * cs - kp * sn; }
        else           { qo = qp * sn + qv * cs; ko = kp * sn + kv * cs; }

        size_t oidx = ((size_t)head * S_ + s) * 64 + lane;
        qt[oidx] = (_Float16)(qo * LOG2E);
        kt[oidx] = (_Float16)ko;
    }
}

// ------------------- transposed MFMA flash attention (dbuf) ----------------
// grid (32 heads, 16 q-tiles of 128), block 256 = 4 waves; wave w owns 32
// queries as 2 q-groups of 16 (one query per lane-column c).
// K/V LDS ping-pong: stage tile j+1 right after the barrier, compute tile j
// while those loads fly -> next barrier's vmcnt drain is mostly hidden.
__global__ __launch_bounds__(256) void attn_mfma_kernel(
    const _Float16* __restrict__ qt, const _Float16* __restrict__ kt,
    const _Float16* __restrict__ vt2, _Float16* __restrict__ ctx)
{
    __shared__ _Float16 Kls[2][4096];
    __shared__ _Float16 Vls[2][4096];

    int head = blockIdx.x, q0 = blockIdx.y * 128;
    int b = head >> 4, rh = head & 15;
    int tid = threadIdx.x, lane = tid & 63, w = tid >> 6;
    int g = lane >> 4, c = lane & 15;

    // Q B-frags + static softmax bound mL = |q~| (log2 units) per q-group
    half8 qf[2][2];
    float mL[2], l_s[2] = {0.f, 0.f};
#pragma unroll
    for (int qg = 0; qg < 2; ++qg) {
        const _Float16* qp =
            qt + ((size_t)head * S_ + q0 + w * 32 + qg * 16 + c) * 64 + 8 * g;
        qf[qg][0] = *(const half8*)qp;
        qf[qg][1] = *(const half8*)(qp + 32);
        float qq = 0.f;
#pragma unroll
        for (int i = 0; i < 8; ++i) {
            float a = (float)qf[qg][0][i], b2 = (float)qf[qg][1][i];
            qq += a * a + b2 * b2;
        }
        qq += __shfl_xor(qq, 16);
        qq += __shfl_xor(qq, 32);
        mL[qg] = sqrtf(qq);       // s_log2 <= |q~|*|k^| = mL  (k^ unit norm)
    }

    floatx4 o_acc[2][4] = {};

    // staging geometry (per wave: K chunks {2w,2w+1}, V chunks {2w,2w+1}).
    // K: lane L -> row ch*8+(L>>3), d-octet (L&7)^(L>>3) (XOR swizzle via
    // global source address). V: vt2 is already the LDS image -> linear copy.
    const _Float16* kg[2]; const _Float16* vg[2];
    int loff[2];
#pragma unroll
    for (int i2 = 0; i2 < 2; ++i2) {
        int ch = 2 * w + i2;
        int krow = ch * 8 + (lane >> 3);
        int koct = (lane & 7) ^ (lane >> 3);
        kg[i2] = kt + ((size_t)head * S_ + krow) * 64 + koct * 8;
        vg[i2] = vt2 + ((size_t)head * 32) * 4096 + ch * 512 + lane * 8;
        loff[i2] = ch * 512;
    }

    int co = c & 7;   // XOR swizzle term for frag reads

    // prologue: stage tile 0 into buffer 0
#pragma unroll
    for (int i2 = 0; i2 < 2; ++i2) {
        gl_lds16(kg[i2], &Kls[0][loff[i2]]);
        gl_lds16(vg[i2], &Vls[0][loff[i2]]);
    }

    for (int jt = 0; jt < 32; ++jt) {
        int cur = jt & 1;
        __syncthreads();              // buf[cur] staged (vmcnt drained); buf[cur^1] free
        if (jt + 1 < 32) {
#pragma unroll
            for (int i2 = 0; i2 < 2; ++i2) {
                gl_lds16(kg[i2] + (size_t)(jt + 1) * 4096, &Kls[cur ^ 1][loff[i2]]);
                gl_lds16(vg[i2] + (size_t)(jt + 1) * 4096, &Vls[cur ^ 1][loff[i2]]);
            }
        }
        const _Float16* Kbuf = Kls[cur];
        const _Float16* Vbuf = Vls[cur];

        // ---- K fragments once, shared by both q-groups ----
        half8 kfr[8];
#pragma unroll
        for (int t = 0; t < 4; ++t) {
            const _Float16* krow = Kbuf + (16 * t + c) * 64;
            kfr[2 * t]     = *(const half8*)(krow + ((g) ^ co) * 8);
            kfr[2 * t + 1] = *(const half8*)(krow + ((4 + g) ^ co) * 8);
        }

        union { half8 v; fp16x2 h2[4]; } pf[2][2];
#pragma unroll
        for (int qg = 0; qg < 2; ++qg) {
            // S^T = K @ Q~^T  (result already in log2 units)
            floatx4 sacc[4];
#pragma unroll
            for (int t = 0; t < 4; ++t) {
                floatx4 z = {};
                z = __builtin_amdgcn_mfma_f32_16x16x32_f16(
                    kfr[2 * t], qf[qg][0], z, 0, 0, 0);
                z = __builtin_amdgcn_mfma_f32_16x16x32_f16(
                    kfr[2 * t + 1], qf[qg][1], z, 0, 0, 0);
                sacc[t] = z;
            }
            // static-max softmax: p = exp2(s - mL); l accumulates per-lane
            float mLq = mL[qg], ps = 0.f;
#pragma unroll
            for (int t = 0; t < 4; ++t)
#pragma unroll
                for (int r = 0; r < 4; ++r) {
                    float p = EXP2(sacc[t][r] - mLq);
                    sacc[t][r] = p;
                    ps += p;
                }
            l_s[qg] += ps;
            pf[qg][0].h2[0] = __builtin_amdgcn_cvt_pkrtz(sacc[0][0], sacc[0][1]);
            pf[qg][0].h2[1] = __builtin_amdgcn_cvt_pkrtz(sacc[0][2], sacc[0][3]);
            pf[qg][0].h2[2] = __builtin_amdgcn_cvt_pkrtz(sacc[1][0], sacc[1][1]);
            pf[qg][0].h2[3] = __builtin_amdgcn_cvt_pkrtz(sacc[1][2], sacc[1][3]);
            pf[qg][1].h2[0] = __builtin_amdgcn_cvt_pkrtz(sacc[2][0], sacc[2][1]);
            pf[qg][1].h2[1] = __builtin_amdgcn_cvt_pkrtz(sacc[2][2], sacc[2][3]);
            pf[qg][1].h2[2] = __builtin_amdgcn_cvt_pkrtz(sacc[3][0], sacc[3][1]);
            pf[qg][1].h2[3] = __builtin_amdgcn_cvt_pkrtz(sacc[3][2], sacc[3][3]);
        }

        // ---- V fragments once, shared; O^T += V^T @ P^T ----
#pragma unroll
        for (int t = 0; t < 4; ++t) {
            const _Float16* vrow = Vbuf + (16 * t + c) * 64;
            half8 v0 = *(const half8*)(vrow + ((g) ^ co) * 8);
            half8 v1 = *(const half8*)(vrow + ((4 + g) ^ co) * 8);
#pragma unroll
            for (int qg = 0; qg < 2; ++qg) {
                o_acc[qg][t] = __builtin_amdgcn_mfma_f32_16x16x32_f16(
                    v0, pf[qg][0].v, o_acc[qg][t], 0, 0, 0);
                o_acc[qg][t] = __builtin_amdgcn_mfma_f32_16x16x32_f16(
                    v1, pf[qg][1].v, o_acc[qg][t], 0, 0, 0);
            }
        }
    }

    // ---- epilogue: l = full sum (per-lane partials over g), O/l -> ctx ----
#pragma unroll
    for (int qg = 0; qg < 2; ++qg) {
        float lt = l_s[qg];
        lt += __shfl_xor(lt, 16);
        lt += __shfl_xor(lt, 32);
        float inv = 1.f / lt;
        size_t rowbase =
            ((size_t)(b * S_ + q0 + w * 32 + qg * 16 + c)) * 1024 + rh * 64;
#pragma unroll
        for (int t = 0; t < 4; ++t) {
            union { half4 v; fp16x2 h2[2]; } e;
            e.h2[0] = __builtin_amdgcn_cvt_pkrtz(o_acc[qg][t][0] * inv,
                                                 o_acc[qg][t][1] * inv);
            e.h2[1] = __builtin_amdgcn_cvt_pkrtz(o_acc[qg][t][2] * inv,
                                                 o_acc[qg][t][3] * inv);
            *(half4*)(ctx + rowbase + 16 * t + 4 * g) = e.v;
        }
    }
}

// ----------- LayerNorm over y0+y1 (split-K partials) -> out ----------------
__global__ __launch_bounds__(256) void ln2_kernel(
    const float* __restrict__ y0, const float* __restrict__ y1,
    const float* __restrict__ g, const float* __restrict__ bb,
    float* __restrict__ out)
{
    int row = blockIdx.x, tid = threadIdx.x;
    float4 a = ((const float4*)(y0 + (size_t)row * 1024))[tid];
    float4 b4 = ((const float4*)(y1 + (size_t)row * 1024))[tid];
    float4 v;
    v.x = a.x + b4.x; v.y = a.y + b4.y; v.z = a.z + b4.z; v.w = a.w + b4.w;
    float sum = v.x + v.y + v.z + v.w;
    float sq  = v.x*v.x + v.y*v.y + v.z*v.z + v.w*v.w;
#pragma unroll
    for (int off = 32; off > 0; off >>= 1) {
        sum += __shfl_xor(sum, off);
        sq  += __shfl_xor(sq,  off);
    }
    __shared__ float rs[4], rq[4];
    int w = tid >> 6;
    if ((tid & 63) == 0) { rs[w] = sum; rq[w] = sq; }
    __syncthreads();
    sum = rs[0] + rs[1] + rs[2] + rs[3];
    sq  = rq[0] + rq[1] + rq[2] + rq[3];
    float mean = sum * (1.f / 1024.f);
    float var  = sq * (1.f / 1024.f) - mean * mean;
    float inv  = rsqrtf(var + 1e-5f);
    float4 gv = ((const float4*)g)[tid];
    float4 bv = ((const float4*)bb)[tid];
    v.x = (v.x - mean) * inv * gv.x + bv.x;
    v.y = (v.y - mean) * inv * gv.y + bv.y;
    v.z = (v.z - mean) * inv * gv.z + bv.z;
    v.w = (v.w - mean) * inv * gv.w + bv.w;
    ((float4*)(out + (size_t)row * 1024))[tid] = v;
}

// ---------------------------------------------------------------------------
extern "C" void kernel_launch(void* const* d_in, const int* in_sizes, int n_in,
                              void* d_out, int out_size, void* d_ws, size_t ws_size,
                              hipStream_t stream)
{
    const float* x     = (const float*)d_in[0];
    const float* pos   = (const float*)d_in[1];
    const float* W_qkv = (const float*)d_in[2];
    const float* b_qkv = (const float*)d_in[3];
    const float* W_out = (const float*)d_in[4];
    const float* b_out = (const float*)d_in[5];
    const float* ln_g  = (const float*)d_in[6];
    const float* ln_b  = (const float*)d_in[7];
    float* out = (float*)d_out;

    // workspace layout (96 MB). y0/y1 overlay the qkv region (dead after prep).
    char* ws = (char*)d_ws;
    _Float16* x_h    = (_Float16*)(ws);                       //  8 MB
    _Float16* wqkv_t = (_Float16*)(ws + ((size_t)8  << 20));  //  6 MB
    _Float16* wout_t = (_Float16*)(ws + ((size_t)14 << 20));  //  2 MB
    float*    qkv    = (float*)   (ws + ((size_t)16 << 20));  // 48 MB
    float*    ypart  = (float*)   (ws + ((size_t)16 << 20));  // 2x16 MB (overlay)
    _Float16* qt_h   = (_Float16*)(ws + ((size_t)64 << 20));  //  8 MB
    _Float16* kt_h   = (_Float16*)(ws + ((size_t)72 << 20));  //  8 MB
    _Float16* vt2_h  = (_Float16*)(ws + ((size_t)80 << 20));  //  8 MB
    _Float16* ctx_h  = (_Float16*)(ws + ((size_t)88 << 20));  //  8 MB

    cast_f16_kernel<<<4096, 256, 0, stream>>>(x, x_h, BS_ * H_);
    transpose_cast_f16<<<dim3(96, 32), 256, 0, stream>>>(W_qkv, wqkv_t, H_, NQKV);
    transpose_cast_f16<<<dim3(32, 32), 256, 0, stream>>>(W_out, wout_t, H_, H_);

    // qkv = x @ W_qkv + b_qkv   (single K-range)
    gemm_f16_mfma<<<dim3(NQKV / 128, BS_ / 128, 1), 256, 0, stream>>>(
        x_h, wqkv_t, b_qkv, nullptr, qkv, BS_, NQKV, H_, H_);

    prep_kernel<<<dim3(32, 32), 256, 0, stream>>>(qkv, pos, qt_h, kt_h, vt2_h);

    attn_mfma_kernel<<<dim3(32, 16), 256, 0, stream>>>(qt_h, kt_h, vt2_h, ctx_h);

    // y0 + y1 = x + ctx @ W_out + b_out   (split-K=2; qkv region is dead now)
    gemm_f16_mfma<<<dim3(H_ / 128, BS_ / 128, 2), 256, 0, stream>>>(
        ctx_h, wout_t, b_out, x, ypart, BS_, H_, H_, H_ / 2);

    ln2_kernel<<<BS_, 256, 0, stream>>>(
        ypart, ypart + (size_t)BS_ * H_, ln_g, ln_b, out);
}

// Round 7
// 232.351 us; speedup vs baseline: 1.1121x; 1.1121x over previous
//
#include <hip/hip_runtime.h>

// ---------------------------------------------------------------------------
// SelfMultiHeadAttn: x[B,S,H] -> LN(x + OutProj(SDPA(RoPE(q), RoPE(k/|k|), v)))
// B=2 S=2048 H=1024 R=16 heads, K=64 head dim. fp32 in/out.
// R7 = R5 base (attn/rope/vtrans known-good) + GEMM K-loop double-buffer
//      (1 barrier/iter, prefetch flies during compute) + qkv GEMM writes f16
//      (halves the 48 MB fp32 write that made qkv the top dispatch in R6).
// ---------------------------------------------------------------------------

#define B_   2
#define S_   2048
#define H_   1024
#define R_   16
#define BS_  (B_*S_)     // 4096 rows
#define NQKV 3072        // R*K*3
#define LOG2E 1.44269504088896f

typedef float    floatx4 __attribute__((ext_vector_type(4)));
typedef _Float16 half8   __attribute__((ext_vector_type(8)));
typedef _Float16 half4   __attribute__((ext_vector_type(4)));
typedef __fp16   fp16x2  __attribute__((ext_vector_type(2)));  // cvt_pkrtz ret

#if __has_builtin(__builtin_amdgcn_exp2f)
#define EXP2(x) __builtin_amdgcn_exp2f(x)
#else
#define EXP2(x) exp2f(x)
#endif

// async global -> LDS, 16 B per lane (lds dest = wave-uniform base + lane*16)
__device__ __forceinline__ void gl_lds16(const _Float16* g, _Float16* l) {
    __builtin_amdgcn_global_load_lds(
        (const __attribute__((address_space(1))) unsigned int*)g,
        (__attribute__((address_space(3))) unsigned int*)l, 16, 0, 0);
}

// ---------------- cast fp32 -> fp16 (vectorized, n % 1024 == 0) ------------
__global__ __launch_bounds__(256) void cast_f16_kernel(
    const float* __restrict__ in, _Float16* __restrict__ out, int n)
{
    int i = (blockIdx.x * 256 + threadIdx.x) * 4;
    if (i >= n) return;
    float4 v = *(const float4*)(in + i);
    half4 h;
    h.x = (_Float16)v.x; h.y = (_Float16)v.y; h.z = (_Float16)v.z; h.w = (_Float16)v.w;
    *(half4*)(out + i) = h;
}

// --------- transpose + cast: in[rows][cols] f32 -> out[cols][rows] f16 -----
__global__ __launch_bounds__(256) void transpose_cast_f16(
    const float* __restrict__ in, _Float16* __restrict__ out, int rows, int cols)
{
    __shared__ float tile[32][33];
    int bx = blockIdx.x * 32;
    int by = blockIdx.y * 32;
    int tx = threadIdx.x & 31, ty = threadIdx.x >> 5;
#pragma unroll
    for (int i = 0; i < 32; i += 8)
        tile[ty + i][tx] = in[(size_t)(by + ty + i) * cols + bx + tx];
    __syncthreads();
#pragma unroll
    for (int i = 0; i < 32; i += 8)
        out[(size_t)(bx + ty + i) * rows + by + tx] = (_Float16)tile[tx][ty + i];
}

// ---------- f16 MFMA GEMM, K-loop double-buffered:  C = A @ Bt^T + bias ----
// F16OUT=true: write f16 to Ch (no resid). F16OUT=false: fp32 +resid to Cf.
// LDS ping-pong: stage K-chunk it+1 right after the barrier; those loads fly
// during this chunk's 16 MFMAs -> next barrier's vmcnt drain is mostly hidden.
//   A: lane holds A[m=lane&15][k = 8*(lane>>4) + j]
//   B: lane holds B[k = 8*(lane>>4) + j][n=lane&15]   (reads Bt[n][k] contig)
//   D: reg r holds D[row = 4*(lane>>4) + r][col = lane&15]
template <bool F16OUT>
__global__ __launch_bounds__(256) void gemm_f16_mfma(
    const _Float16* __restrict__ A, const _Float16* __restrict__ Bt,
    const float* __restrict__ bias, const float* __restrict__ resid,
    float* __restrict__ Cf, _Float16* __restrict__ Ch, int M, int N, int Kd)
{
    __shared__ _Float16 Als[2][4096];
    __shared__ _Float16 Bls[2][4096];
    int tid  = threadIdx.x;
    int lane = tid & 63, w = tid >> 6;
    int wr = w >> 1, wc = w & 1;
    int fr = lane & 15, fq = lane >> 4;
    int m0 = blockIdx.y * 128, n0 = blockIdx.x * 128;

    floatx4 acc[4][4] = {};

    // staging geometry: wave w stages chunks {2w, 2w+1} of A and B (1KB each:
    // 16 rows x 32 halves; lane L -> row ch*16+(L>>2), col (L&3)*8).
    const _Float16* ga[2]; const _Float16* gb[2];
    int loff[2];
#pragma unroll
    for (int i2 = 0; i2 < 2; ++i2) {
        int ch = 2 * w + i2;
        int row = ch * 16 + (lane >> 2), col = (lane & 3) * 8;
        ga[i2] = A  + (size_t)(m0 + row) * Kd + col;
        gb[i2] = Bt + (size_t)(n0 + row) * Kd + col;
        loff[i2] = ch * 512;
    }

    int nIter = Kd >> 5;
    // prologue: stage chunk 0 into buffer 0
#pragma unroll
    for (int i2 = 0; i2 < 2; ++i2) {
        gl_lds16(ga[i2], &Als[0][loff[i2]]);
        gl_lds16(gb[i2], &Bls[0][loff[i2]]);
    }

    for (int it = 0; it < nIter; ++it) {
        int cur = it & 1;
        __syncthreads();               // buf[cur] staged; buf[cur^1] free
        if (it + 1 < nIter) {
            int k1 = (it + 1) << 5;
#pragma unroll
            for (int i2 = 0; i2 < 2; ++i2) {
                gl_lds16(ga[i2] + k1, &Als[cur ^ 1][loff[i2]]);
                gl_lds16(gb[i2] + k1, &Bls[cur ^ 1][loff[i2]]);
            }
        }
        const _Float16* Ab = Als[cur];
        const _Float16* Bb = Bls[cur];
        half8 af[4], bf[4];
#pragma unroll
        for (int i = 0; i < 4; ++i)
            af[i] = *(const half8*)(Ab + (wr * 64 + i * 16 + fr) * 32 + fq * 8);
#pragma unroll
        for (int j = 0; j < 4; ++j)
            bf[j] = *(const half8*)(Bb + (wc * 64 + j * 16 + fr) * 32 + fq * 8);
#pragma unroll
        for (int i = 0; i < 4; ++i)
#pragma unroll
            for (int j = 0; j < 4; ++j)
                acc[i][j] = __builtin_amdgcn_mfma_f32_16x16x32_f16(
                    af[i], bf[j], acc[i][j], 0, 0, 0);
    }

#pragma unroll
    for (int i = 0; i < 4; ++i)
#pragma unroll
        for (int j = 0; j < 4; ++j)
#pragma unroll
            for (int r2 = 0; r2 < 4; ++r2) {
                int row = m0 + wr * 64 + i * 16 + fq * 4 + r2;
                int col = n0 + wc * 64 + j * 16 + fr;
                float v = acc[i][j][r2] + bias[col];
                if constexpr (F16OUT) {
                    Ch[(size_t)row * N + col] = (_Float16)v;
                } else {
                    if (resid) v += resid[(size_t)row * N + col];
                    Cf[(size_t)row * N + col] = v;
                }
            }
}

// ---------- k-normalize + RoPE; q~ pre-scaled by LOG2E; f16 head-major -----
// qkvh[bs][3072] f16: per head r: q at r*192+[0,64), k at +64, v at +128.
__global__ __launch_bounds__(256) void rope_kernel(
    const _Float16* __restrict__ qkvh, const float* __restrict__ pos,
    _Float16* __restrict__ qt, _Float16* __restrict__ kt)
{
    int task = blockIdx.x * 4 + (threadIdx.x >> 6);   // bs*16 + r
    int lane = threadIdx.x & 63;
    int r = task & 15, bs = task >> 4;
    int b = bs >> 11, s = bs & 2047;

    const _Float16* base = qkvh + (size_t)bs * NQKV + r * 192;
    float qv = (float)base[lane];
    float kv = (float)base[64 + lane];

    float ss = kv * kv;
#pragma unroll
    for (int off = 32; off > 0; off >>= 1) ss += __shfl_xor(ss, off);
    kv *= rsqrtf(ss);

    int j = lane & 31;
    float sn = pos[(size_t)bs * 64 + j];
    float cs = pos[(size_t)bs * 64 + 32 + j];
    float qp = __shfl_xor(qv, 32);
    float kp = __shfl_xor(kv, 32);
    float qo, ko;
    if (lane < 32) { qo = qv * cs - qp * sn; ko = kv * cs - kp * sn; }
    else           { qo = qp * sn + qv * cs; ko = kp * sn + kv * cs; }

    size_t oidx = ((size_t)(b * 16 + r) * S_ + s) * 64 + lane;
    qt[oidx] = (_Float16)(qo * LOG2E);   // fold log2(e) into q~
    kt[oidx] = (_Float16)ko;
}

// ------- V transpose into pre-baked attention LDS image -----------------
// vt2[head][tau][d][P]: position P of row d holds V[key_of(P,d)][d] with
// op=P>>3, ol=op^(d&7): key_of = 32*(ol>>2)+16*((P>>2)&1)+4*(ol&3)+(P&3)
// (bakes the PV keymap permutation and the bank XOR swizzle).
__global__ __launch_bounds__(256) void vtrans_kernel(
    const _Float16* __restrict__ qkvh, _Float16* __restrict__ vt2)
{
    __shared__ float tile[64][65];
    int head = blockIdx.x, tau = blockIdx.y;
    int s0 = tau * 64;
    int b = head >> 4, rh = head & 15;
    int tx = threadIdx.x & 63, ty = threadIdx.x >> 6;
#pragma unroll
    for (int si = ty; si < 64; si += 4)
        tile[si][tx] = (float)qkvh[(size_t)(b * S_ + s0 + si) * NQKV + rh * 192 + 128 + tx];
    __syncthreads();
    int P = tx;
    int op = P >> 3;
    int hi = (P >> 2) & 1, lo = P & 3;
#pragma unroll
    for (int d = ty; d < 64; d += 4) {
        int ol = op ^ (d & 7);
        int key = 32 * (ol >> 2) + 16 * hi + 4 * (ol & 3) + lo;
        vt2[(((size_t)head * 32 + tau) * 64 + d) * 64 + P] = (_Float16)tile[key][d];
    }
}

// ------------------- transposed MFMA flash attention (R5, known-good) ------
// grid (32 heads, 16 q-tiles of 128), block 256 = 4 waves; wave w owns 32
// queries as 2 q-groups of 16 (one query per lane-column c). Per 64-key tile:
//   kfr = K frags (8 ds_read_b128, shared by both q-groups)
//   S^T = K @ Q~^T (log2-scaled), p = exp2(s - |q~|) (static max), l partial
//   vfr = V frags (8 reads, shared);  O^T += V^T @ P^T
__global__ __launch_bounds__(256) void attn_mfma_kernel(
    const _Float16* __restrict__ qt, const _Float16* __restrict__ kt,
    const _Float16* __restrict__ vt2, _Float16* __restrict__ ctx)
{
    __shared__ _Float16 Kls[64 * 64];
    __shared__ _Float16 Vls[64 * 64];

    int head = blockIdx.x, q0 = blockIdx.y * 128;
    int b = head >> 4, rh = head & 15;
    int tid = threadIdx.x, lane = tid & 63, w = tid >> 6;
    int g = lane >> 4, c = lane & 15;

    // Q B-frags + static softmax bound mL = |q~| (log2 units) per q-group
    half8 qf[2][2];
    float mL[2], l_s[2] = {0.f, 0.f};
#pragma unroll
    for (int qg = 0; qg < 2; ++qg) {
        const _Float16* qp =
            qt + ((size_t)head * S_ + q0 + w * 32 + qg * 16 + c) * 64 + 8 * g;
        qf[qg][0] = *(const half8*)qp;
        qf[qg][1] = *(const half8*)(qp + 32);
        float qq = 0.f;
#pragma unroll
        for (int i = 0; i < 8; ++i) {
            float a = (float)qf[qg][0][i], b2 = (float)qf[qg][1][i];
            qq += a * a + b2 * b2;
        }
        qq += __shfl_xor(qq, 16);
        qq += __shfl_xor(qq, 32);
        mL[qg] = sqrtf(qq);       // s_log2 <= |q~|*|k^| = mL  (k^ unit norm)
    }

    floatx4 o_acc[2][4] = {};

    // staging (per wave: K chunks {2w,2w+1}, V chunks {2w,2w+1}, 1KB each).
    // K: lane L -> row ch*8+(L>>3), d-octet (L&7)^(L>>3)  (XOR swizzle via
    // global source address). V: vt2 is already the LDS image -> linear copy.
    const _Float16* kg[2]; const _Float16* vg[2];
    _Float16 *kl_[2], *vl_[2];
#pragma unroll
    for (int i2 = 0; i2 < 2; ++i2) {
        int ch = 2 * w + i2;
        int krow = ch * 8 + (lane >> 3);
        int koct = (lane & 7) ^ (lane >> 3);
        kg[i2] = kt + ((size_t)head * S_ + krow) * 64 + koct * 8;
        kl_[i2] = Kls + ch * 512;
        vg[i2] = vt2 + ((size_t)head * 32) * 4096 + ch * 512 + lane * 8;
        vl_[i2] = Vls + ch * 512;
    }

    int co = c & 7;   // XOR swizzle term for frag reads

    for (int j0 = 0; j0 < S_; j0 += 64) {
        __syncthreads();                       // prev tile's frag reads done
#pragma unroll
        for (int i2 = 0; i2 < 2; ++i2) {
            gl_lds16(kg[i2] + (size_t)j0 * 64, kl_[i2]);
            gl_lds16(vg[i2] + (size_t)(j0 >> 6) * 4096, vl_[i2]);
        }
        __syncthreads();                       // vmcnt drained -> LDS ready

        // ---- K fragments once, shared by both q-groups ----
        half8 kfr[8];
#pragma unroll
        for (int t = 0; t < 4; ++t) {
            const _Float16* krow = Kls + (16 * t + c) * 64;
            kfr[2 * t]     = *(const half8*)(krow + ((g) ^ co) * 8);
            kfr[2 * t + 1] = *(const half8*)(krow + ((4 + g) ^ co) * 8);
        }

        union { half8 v; fp16x2 h2[4]; } pf[2][2];
#pragma unroll
        for (int qg = 0; qg < 2; ++qg) {
            // S^T = K @ Q~^T  (result already in log2 units)
            floatx4 sacc[4];
#pragma unroll
            for (int t = 0; t < 4; ++t) {
                floatx4 z = {};
                z = __builtin_amdgcn_mfma_f32_16x16x32_f16(
                    kfr[2 * t], qf[qg][0], z, 0, 0, 0);
                z = __builtin_amdgcn_mfma_f32_16x16x32_f16(
                    kfr[2 * t + 1], qf[qg][1], z, 0, 0, 0);
                sacc[t] = z;
            }
            // static-max softmax: p = exp2(s - mL); l accumulates per-lane
            float mLq = mL[qg], ps = 0.f;
#pragma unroll
            for (int t = 0; t < 4; ++t)
#pragma unroll
                for (int r = 0; r < 4; ++r) {
                    float p = EXP2(sacc[t][r] - mLq);
                    sacc[t][r] = p;
                    ps += p;
                }
            l_s[qg] += ps;
            pf[qg][0].h2[0] = __builtin_amdgcn_cvt_pkrtz(sacc[0][0], sacc[0][1]);
            pf[qg][0].h2[1] = __builtin_amdgcn_cvt_pkrtz(sacc[0][2], sacc[0][3]);
            pf[qg][0].h2[2] = __builtin_amdgcn_cvt_pkrtz(sacc[1][0], sacc[1][1]);
            pf[qg][0].h2[3] = __builtin_amdgcn_cvt_pkrtz(sacc[1][2], sacc[1][3]);
            pf[qg][1].h2[0] = __builtin_amdgcn_cvt_pkrtz(sacc[2][0], sacc[2][1]);
            pf[qg][1].h2[1] = __builtin_amdgcn_cvt_pkrtz(sacc[2][2], sacc[2][3]);
            pf[qg][1].h2[2] = __builtin_amdgcn_cvt_pkrtz(sacc[3][0], sacc[3][1]);
            pf[qg][1].h2[3] = __builtin_amdgcn_cvt_pkrtz(sacc[3][2], sacc[3][3]);
        }

        // ---- V fragments once, shared; O^T += V^T @ P^T ----
#pragma unroll
        for (int t = 0; t < 4; ++t) {
            const _Float16* vrow = Vls + (16 * t + c) * 64;
            half8 v0 = *(const half8*)(vrow + ((g) ^ co) * 8);
            half8 v1 = *(const half8*)(vrow + ((4 + g) ^ co) * 8);
#pragma unroll
            for (int qg = 0; qg < 2; ++qg) {
                o_acc[qg][t] = __builtin_amdgcn_mfma_f32_16x16x32_f16(
                    v0, pf[qg][0].v, o_acc[qg][t], 0, 0, 0);
                o_acc[qg][t] = __builtin_amdgcn_mfma_f32_16x16x32_f16(
                    v1, pf[qg][1].v, o_acc[qg][t], 0, 0, 0);
            }
        }
    }

    // ---- epilogue: l = full sum (per-lane partials over g), O/l -> ctx ----
#pragma unroll
    for (int qg = 0; qg < 2; ++qg) {
        float lt = l_s[qg];
        lt += __shfl_xor(lt, 16);
        lt += __shfl_xor(lt, 32);
        float inv = 1.f / lt;
        size_t rowbase =
            ((size_t)(b * S_ + q0 + w * 32 + qg * 16 + c)) * 1024 + rh * 64;
#pragma unroll
        for (int t = 0; t < 4; ++t) {
            union { half4 v; fp16x2 h2[2]; } e;
            e.h2[0] = __builtin_amdgcn_cvt_pkrtz(o_acc[qg][t][0] * inv,
                                                 o_acc[qg][t][1] * inv);
            e.h2[1] = __builtin_amdgcn_cvt_pkrtz(o_acc[qg][t][2] * inv,
                                                 o_acc[qg][t][3] * inv);
            *(half4*)(ctx + rowbase + 16 * t + 4 * g) = e.v;
        }
    }
}

// --------------------- LayerNorm in place on y[4096][1024] -----------------
__global__ __launch_bounds__(256) void ln_kernel(
    float* __restrict__ y, const float* __restrict__ g, const float* __restrict__ bb)
{
    int row = blockIdx.x, tid = threadIdx.x;
    float* p = y + (size_t)row * 1024;
    float4 v = ((const float4*)p)[tid];
    float sum = v.x + v.y + v.z + v.w;
    float sq  = v.x*v.x + v.y*v.y + v.z*v.z + v.w*v.w;
#pragma unroll
    for (int off = 32; off > 0; off >>= 1) {
        sum += __shfl_xor(sum, off);
        sq  += __shfl_xor(sq,  off);
    }
    __shared__ float rs[4], rq[4];
    int w = tid >> 6;
    if ((tid & 63) == 0) { rs[w] = sum; rq[w] = sq; }
    __syncthreads();
    sum = rs[0] + rs[1] + rs[2] + rs[3];
    sq  = rq[0] + rq[1] + rq[2] + rq[3];
    float mean = sum * (1.f / 1024.f);
    float var  = sq * (1.f / 1024.f) - mean * mean;
    float inv  = rsqrtf(var + 1e-5f);
    float4 gv = ((const float4*)g)[tid];
    float4 bv = ((const float4*)bb)[tid];
    v.x = (v.x - mean) * inv * gv.x + bv.x;
    v.y = (v.y - mean) * inv * gv.y + bv.y;
    v.z = (v.z - mean) * inv * gv.z + bv.z;
    v.w = (v.w - mean) * inv * gv.w + bv.w;
    ((float4*)p)[tid] = v;
}

// ---------------------------------------------------------------------------
extern "C" void kernel_launch(void* const* d_in, const int* in_sizes, int n_in,
                              void* d_out, int out_size, void* d_ws, size_t ws_size,
                              hipStream_t stream)
{
    const float* x     = (const float*)d_in[0];
    const float* pos   = (const float*)d_in[1];
    const float* W_qkv = (const float*)d_in[2];
    const float* b_qkv = (const float*)d_in[3];
    const float* W_out = (const float*)d_in[4];
    const float* b_out = (const float*)d_in[5];
    const float* ln_g  = (const float*)d_in[6];
    const float* ln_b  = (const float*)d_in[7];
    float* out = (float*)d_out;

    // workspace layout (72 MB)
    char* ws = (char*)d_ws;
    _Float16* x_h    = (_Float16*)(ws);                       //  8 MB
    _Float16* wqkv_t = (_Float16*)(ws + ((size_t)8  << 20));  //  6 MB
    _Float16* wout_t = (_Float16*)(ws + ((size_t)14 << 20));  //  2 MB
    _Float16* qkvh   = (_Float16*)(ws + ((size_t)16 << 20));  // 24 MB (f16!)
    _Float16* qt_h   = (_Float16*)(ws + ((size_t)40 << 20));  //  8 MB
    _Float16* kt_h   = (_Float16*)(ws + ((size_t)48 << 20));  //  8 MB
    _Float16* vt2_h  = (_Float16*)(ws + ((size_t)56 << 20));  //  8 MB
    _Float16* ctx_h  = (_Float16*)(ws + ((size_t)64 << 20));  //  8 MB

    cast_f16_kernel<<<4096, 256, 0, stream>>>(x, x_h, BS_ * H_);
    transpose_cast_f16<<<dim3(96, 32), 256, 0, stream>>>(W_qkv, wqkv_t, H_, NQKV);
    transpose_cast_f16<<<dim3(32, 32), 256, 0, stream>>>(W_out, wout_t, H_, H_);

    // qkv (f16) = x @ W_qkv + b_qkv
    gemm_f16_mfma<true><<<dim3(NQKV / 128, BS_ / 128), 256, 0, stream>>>(
        x_h, wqkv_t, b_qkv, nullptr, nullptr, qkvh, BS_, NQKV, H_);

    rope_kernel<<<BS_ * R_ / 4, 256, 0, stream>>>(qkvh, pos, qt_h, kt_h);
    vtrans_kernel<<<dim3(32, 32), 256, 0, stream>>>(qkvh, vt2_h);

    attn_mfma_kernel<<<dim3(32, 16), 256, 0, stream>>>(qt_h, kt_h, vt2_h, ctx_h);

    // out (fp32) = x + ctx @ W_out + b_out
    gemm_f16_mfma<false><<<dim3(H_ / 128, BS_ / 128), 256, 0, stream>>>(
        ctx_h, wout_t, b_out, x, out, nullptr, BS_, H_, H_);

    ln_kernel<<<BS_, 256, 0, stream>>>(out, ln_g, ln_b);
}

// Round 8
// 229.441 us; speedup vs baseline: 1.1262x; 1.0127x over previous
//
#include <hip/hip_runtime.h>

// ---------------------------------------------------------------------------
// SelfMultiHeadAttn: x[B,S,H] -> LN(x + OutProj(SDPA(RoPE(q), RoPE(k/|k|), v)))
// B=2 S=2048 H=1024 R=16 heads, K=64 head dim. fp32 in/out.
// R8 = R7 + (1) attn: static-max subtract folded into MFMA acc-init, raw
//      v_exp_f32 guaranteed (asm fallback); (2) fused cast+transposes kernel;
//      (3) fused rope+vtrans kernel. 6 launches total.
// ---------------------------------------------------------------------------

#define B_   2
#define S_   2048
#define H_   1024
#define R_   16
#define BS_  (B_*S_)     // 4096 rows
#define NQKV 3072        // R*K*3
#define LOG2E 1.44269504088896f

typedef float    floatx4 __attribute__((ext_vector_type(4)));
typedef _Float16 half8   __attribute__((ext_vector_type(8)));
typedef _Float16 half4   __attribute__((ext_vector_type(4)));
typedef __fp16   fp16x2  __attribute__((ext_vector_type(2)));  // cvt_pkrtz ret

// raw 2^x: v_exp_f32 (1 trans-op). Inputs here are <= 0 (static-max) so no
// range reduction needed; s_nop 0 covers the trans->VALU consumer hazard.
__device__ __forceinline__ float exp2_raw(float x) {
#if __has_builtin(__builtin_amdgcn_exp2f)
    return __builtin_amdgcn_exp2f(x);
#else
    float r;
    asm("v_exp_f32 %0, %1\n\ts_nop 0" : "=v"(r) : "v"(x));
    return r;
#endif
}

// async global -> LDS, 16 B per lane (lds dest = wave-uniform base + lane*16)
__device__ __forceinline__ void gl_lds16(const _Float16* g, _Float16* l) {
    __builtin_amdgcn_global_load_lds(
        (const __attribute__((address_space(1))) unsigned int*)g,
        (__attribute__((address_space(3))) unsigned int*)l, 16, 0, 0);
}

// ------- fused preprocessing: x cast + W_qkv^T + W_out^T (one launch) ------
// grid 8192: [0,4096) cast x; [4096,7168) W_qkv transpose; [7168,8192) W_out.
__global__ __launch_bounds__(256) void prep0_kernel(
    const float* __restrict__ x, _Float16* __restrict__ x_h,
    const float* __restrict__ W_qkv, _Float16* __restrict__ wqkv_t,
    const float* __restrict__ W_out, _Float16* __restrict__ wout_t)
{
    __shared__ float tile[32][33];
    int bid = blockIdx.x, tid = threadIdx.x;
    if (bid < 4096) {
        int i = bid * 1024 + tid * 4;
        float4 v = *(const float4*)(x + i);
        half4 h;
        h.x = (_Float16)v.x; h.y = (_Float16)v.y;
        h.z = (_Float16)v.z; h.w = (_Float16)v.w;
        *(half4*)(x_h + i) = h;
        return;
    }
    const float* in; _Float16* out; int rows, cols, bx, by;
    if (bid < 7168) {
        int t = bid - 4096;
        in = W_qkv; out = wqkv_t; rows = H_; cols = NQKV;
        bx = t % 96; by = t / 96;
    } else {
        int t = bid - 7168;
        in = W_out; out = wout_t; rows = H_; cols = H_;
        bx = t & 31; by = t >> 5;
    }
    int cx = bx * 32, ry = by * 32;
    int tx = tid & 31, ty = tid >> 5;   // ty 0..7
#pragma unroll
    for (int i = 0; i < 32; i += 8)
        tile[ty + i][tx] = in[(size_t)(ry + ty + i) * cols + cx + tx];
    __syncthreads();
#pragma unroll
    for (int i = 0; i < 32; i += 8)
        out[(size_t)(cx + ty + i) * rows + ry + tx] = (_Float16)tile[tx][ty + i];
}

// ---------- f16 MFMA GEMM, K-loop double-buffered:  C = A @ Bt^T + bias ----
// F16OUT=true: write f16 to Ch (no resid). F16OUT=false: fp32 +resid to Cf.
//   A: lane holds A[m=lane&15][k = 8*(lane>>4) + j]
//   B: lane holds B[k = 8*(lane>>4) + j][n=lane&15]   (reads Bt[n][k] contig)
//   D: reg r holds D[row = 4*(lane>>4) + r][col = lane&15]
template <bool F16OUT>
__global__ __launch_bounds__(256) void gemm_f16_mfma(
    const _Float16* __restrict__ A, const _Float16* __restrict__ Bt,
    const float* __restrict__ bias, const float* __restrict__ resid,
    float* __restrict__ Cf, _Float16* __restrict__ Ch, int M, int N, int Kd)
{
    __shared__ _Float16 Als[2][4096];
    __shared__ _Float16 Bls[2][4096];
    int tid  = threadIdx.x;
    int lane = tid & 63, w = tid >> 6;
    int wr = w >> 1, wc = w & 1;
    int fr = lane & 15, fq = lane >> 4;
    int m0 = blockIdx.y * 128, n0 = blockIdx.x * 128;

    floatx4 acc[4][4] = {};

    const _Float16* ga[2]; const _Float16* gb[2];
    int loff[2];
#pragma unroll
    for (int i2 = 0; i2 < 2; ++i2) {
        int ch = 2 * w + i2;
        int row = ch * 16 + (lane >> 2), col = (lane & 3) * 8;
        ga[i2] = A  + (size_t)(m0 + row) * Kd + col;
        gb[i2] = Bt + (size_t)(n0 + row) * Kd + col;
        loff[i2] = ch * 512;
    }

    int nIter = Kd >> 5;
#pragma unroll
    for (int i2 = 0; i2 < 2; ++i2) {
        gl_lds16(ga[i2], &Als[0][loff[i2]]);
        gl_lds16(gb[i2], &Bls[0][loff[i2]]);
    }

    for (int it = 0; it < nIter; ++it) {
        int cur = it & 1;
        __syncthreads();               // buf[cur] staged; buf[cur^1] free
        if (it + 1 < nIter) {
            int k1 = (it + 1) << 5;
#pragma unroll
            for (int i2 = 0; i2 < 2; ++i2) {
                gl_lds16(ga[i2] + k1, &Als[cur ^ 1][loff[i2]]);
                gl_lds16(gb[i2] + k1, &Bls[cur ^ 1][loff[i2]]);
            }
        }
        const _Float16* Ab = Als[cur];
        const _Float16* Bb = Bls[cur];
        half8 af[4], bf[4];
#pragma unroll
        for (int i = 0; i < 4; ++i)
            af[i] = *(const half8*)(Ab + (wr * 64 + i * 16 + fr) * 32 + fq * 8);
#pragma unroll
        for (int j = 0; j < 4; ++j)
            bf[j] = *(const half8*)(Bb + (wc * 64 + j * 16 + fr) * 32 + fq * 8);
#pragma unroll
        for (int i = 0; i < 4; ++i)
#pragma unroll
            for (int j = 0; j < 4; ++j)
                acc[i][j] = __builtin_amdgcn_mfma_f32_16x16x32_f16(
                    af[i], bf[j], acc[i][j], 0, 0, 0);
    }

#pragma unroll
    for (int i = 0; i < 4; ++i)
#pragma unroll
        for (int j = 0; j < 4; ++j)
#pragma unroll
            for (int r2 = 0; r2 < 4; ++r2) {
                int row = m0 + wr * 64 + i * 16 + fq * 4 + r2;
                int col = n0 + wc * 64 + j * 16 + fr;
                float v = acc[i][j][r2] + bias[col];
                if constexpr (F16OUT) {
                    Ch[(size_t)row * N + col] = (_Float16)v;
                } else {
                    if (resid) v += resid[(size_t)row * N + col];
                    Cf[(size_t)row * N + col] = v;
                }
            }
}

// ------- fused prep1: k-norm + RoPE -> qt/kt f16; V -> vt2 LDS image -------
// grid (head 32, s-tile 32), block 256 = 4 waves.
// vt2[head][tau][d][P]: position P of row d holds V[key_of(P,d)][d] with
// op=P>>3, ol=op^(d&7): key_of = 32*(ol>>2)+16*((P>>2)&1)+4*(ol&3)+(P&3)
// (bakes PV keymap + bank XOR swizzle). q~ pre-scaled by LOG2E.
__global__ __launch_bounds__(256) void prep1_kernel(
    const _Float16* __restrict__ qkvh, const float* __restrict__ pos,
    _Float16* __restrict__ qt, _Float16* __restrict__ kt,
    _Float16* __restrict__ vt2)
{
    __shared__ float tile[64][65];
    int head = blockIdx.x, tau = blockIdx.y;
    int s0 = tau * 64;
    int b = head >> 4, rh = head & 15;
    int lane = threadIdx.x & 63, w = threadIdx.x >> 6;

    // ---- V slice -> LDS -> permuted image ----
#pragma unroll
    for (int si = w; si < 64; si += 4)
        tile[si][lane] =
            (float)qkvh[(size_t)(b * S_ + s0 + si) * NQKV + rh * 192 + 128 + lane];
    __syncthreads();
    {
        int P = lane;
        int op = P >> 3;
        int hi = (P >> 2) & 1, lo = P & 3;
#pragma unroll
        for (int d = w; d < 64; d += 4) {
            int ol = op ^ (d & 7);
            int key = 32 * (ol >> 2) + 16 * hi + 4 * (ol & 3) + lo;
            vt2[(((size_t)head * 32 + tau) * 64 + d) * 64 + P] = (_Float16)tile[key][d];
        }
    }

    // ---- RoPE + k-norm: wave w handles rows s0 + w*16 + i ----
    for (int i = 0; i < 16; ++i) {
        int s = s0 + w * 16 + i;
        int bs = b * S_ + s;
        const _Float16* base = qkvh + (size_t)bs * NQKV + rh * 192;
        float qv = (float)base[lane];
        float kv = (float)base[64 + lane];

        float ss = kv * kv;
#pragma unroll
        for (int off = 32; off > 0; off >>= 1) ss += __shfl_xor(ss, off);
        kv *= rsqrtf(ss);

        int j = lane & 31;
        float sn = pos[(size_t)bs * 64 + j];
        float cs = pos[(size_t)bs * 64 + 32 + j];
        float qp = __shfl_xor(qv, 32);
        float kp = __shfl_xor(kv, 32);
        float qo, ko;
        if (lane < 32) { qo = qv * cs - qp * sn; ko = kv * cs - kp * sn; }
        else           { qo = qp * sn + qv * cs; ko = kp * sn + kv * cs; }

        size_t oidx = ((size_t)head * S_ + s) * 64 + lane;
        qt[oidx] = (_Float16)(qo * LOG2E);   // fold log2(e) into q~
        kt[oidx] = (_Float16)ko;
    }
}

// ------------------- transposed MFMA flash attention -----------------------
// grid (32 heads, 16 q-tiles of 128), block 256 = 4 waves; wave w owns 32
// queries as 2 q-groups of 16 (one query per lane-column c). Per 64-key tile:
//   kfr = K frags (8 ds_read_b128, shared by both q-groups)
//   S^T - mL = K @ Q~^T + (-mL)  (subtract via MFMA acc-init, free)
//   p = exp2(.) raw v_exp_f32; l partial per-lane
//   O^T += V^T @ P^T  (V frags shared)
__global__ __launch_bounds__(256) void attn_mfma_kernel(
    const _Float16* __restrict__ qt, const _Float16* __restrict__ kt,
    const _Float16* __restrict__ vt2, _Float16* __restrict__ ctx)
{
    __shared__ _Float16 Kls[64 * 64];
    __shared__ _Float16 Vls[64 * 64];

    int head = blockIdx.x, q0 = blockIdx.y * 128;
    int b = head >> 4, rh = head & 15;
    int tid = threadIdx.x, lane = tid & 63, w = tid >> 6;
    int g = lane >> 4, c = lane & 15;

    // Q B-frags + static softmax bound mL = |q~| (log2 units) per q-group
    half8 qf[2][2];
    float mL[2], l_s[2] = {0.f, 0.f};
#pragma unroll
    for (int qg = 0; qg < 2; ++qg) {
        const _Float16* qp =
            qt + ((size_t)head * S_ + q0 + w * 32 + qg * 16 + c) * 64 + 8 * g;
        qf[qg][0] = *(const half8*)qp;
        qf[qg][1] = *(const half8*)(qp + 32);
        float qq = 0.f;
#pragma unroll
        for (int i = 0; i < 8; ++i) {
            float a = (float)qf[qg][0][i], b2 = (float)qf[qg][1][i];
            qq += a * a + b2 * b2;
        }
        qq += __shfl_xor(qq, 16);
        qq += __shfl_xor(qq, 32);
        mL[qg] = sqrtf(qq);       // s_log2 <= |q~|*|k^| = mL  (k^ unit norm)
    }

    floatx4 o_acc[2][4] = {};

    // staging (per wave: K chunks {2w,2w+1}, V chunks {2w,2w+1}, 1KB each).
    // K: lane L -> row ch*8+(L>>3), d-octet (L&7)^(L>>3)  (XOR swizzle via
    // global source address). V: vt2 is already the LDS image -> linear copy.
    const _Float16* kg[2]; const _Float16* vg[2];
    _Float16 *kl_[2], *vl_[2];
#pragma unroll
    for (int i2 = 0; i2 < 2; ++i2) {
        int ch = 2 * w + i2;
        int krow = ch * 8 + (lane >> 3);
        int koct = (lane & 7) ^ (lane >> 3);
        kg[i2] = kt + ((size_t)head * S_ + krow) * 64 + koct * 8;
        kl_[i2] = Kls + ch * 512;
        vg[i2] = vt2 + ((size_t)head * 32) * 4096 + ch * 512 + lane * 8;
        vl_[i2] = Vls + ch * 512;
    }

    int co = c & 7;   // XOR swizzle term for frag reads

    for (int j0 = 0; j0 < S_; j0 += 64) {
        __syncthreads();                       // prev tile's frag reads done
#pragma unroll
        for (int i2 = 0; i2 < 2; ++i2) {
            gl_lds16(kg[i2] + (size_t)j0 * 64, kl_[i2]);
            gl_lds16(vg[i2] + (size_t)(j0 >> 6) * 4096, vl_[i2]);
        }
        __syncthreads();                       // vmcnt drained -> LDS ready

        // ---- K fragments once, shared by both q-groups ----
        half8 kfr[8];
#pragma unroll
        for (int t = 0; t < 4; ++t) {
            const _Float16* krow = Kls + (16 * t + c) * 64;
            kfr[2 * t]     = *(const half8*)(krow + ((g) ^ co) * 8);
            kfr[2 * t + 1] = *(const half8*)(krow + ((4 + g) ^ co) * 8);
        }

        union { half8 v; fp16x2 h2[4]; } pf[2][2];
#pragma unroll
        for (int qg = 0; qg < 2; ++qg) {
            // S^T - mL = K @ Q~^T + (-mL): subtract folded into acc-init
            float negm = -mL[qg];
            floatx4 zinit = {negm, negm, negm, negm};
            floatx4 sacc[4];
#pragma unroll
            for (int t = 0; t < 4; ++t) {
                floatx4 z = zinit;
                z = __builtin_amdgcn_mfma_f32_16x16x32_f16(
                    kfr[2 * t], qf[qg][0], z, 0, 0, 0);
                z = __builtin_amdgcn_mfma_f32_16x16x32_f16(
                    kfr[2 * t + 1], qf[qg][1], z, 0, 0, 0);
                sacc[t] = z;
            }
            // p = exp2(s - mL)  (raw v_exp_f32); l accumulates per-lane
            float ps = 0.f;
#pragma unroll
            for (int t = 0; t < 4; ++t)
#pragma unroll
                for (int r = 0; r < 4; ++r) {
                    float p = exp2_raw(sacc[t][r]);
                    sacc[t][r] = p;
                    ps += p;
                }
            l_s[qg] += ps;
            pf[qg][0].h2[0] = __builtin_amdgcn_cvt_pkrtz(sacc[0][0], sacc[0][1]);
            pf[qg][0].h2[1] = __builtin_amdgcn_cvt_pkrtz(sacc[0][2], sacc[0][3]);
            pf[qg][0].h2[2] = __builtin_amdgcn_cvt_pkrtz(sacc[1][0], sacc[1][1]);
            pf[qg][0].h2[3] = __builtin_amdgcn_cvt_pkrtz(sacc[1][2], sacc[1][3]);
            pf[qg][1].h2[0] = __builtin_amdgcn_cvt_pkrtz(sacc[2][0], sacc[2][1]);
            pf[qg][1].h2[1] = __builtin_amdgcn_cvt_pkrtz(sacc[2][2], sacc[2][3]);
            pf[qg][1].h2[2] = __builtin_amdgcn_cvt_pkrtz(sacc[3][0], sacc[3][1]);
            pf[qg][1].h2[3] = __builtin_amdgcn_cvt_pkrtz(sacc[3][2], sacc[3][3]);
        }

        // ---- V fragments once, shared; O^T += V^T @ P^T ----
#pragma unroll
        for (int t = 0; t < 4; ++t) {
            const _Float16* vrow = Vls + (16 * t + c) * 64;
            half8 v0 = *(const half8*)(vrow + ((g) ^ co) * 8);
            half8 v1 = *(const half8*)(vrow + ((4 + g) ^ co) * 8);
#pragma unroll
            for (int qg = 0; qg < 2; ++qg) {
                o_acc[qg][t] = __builtin_amdgcn_mfma_f32_16x16x32_f16(
                    v0, pf[qg][0].v, o_acc[qg][t], 0, 0, 0);
                o_acc[qg][t] = __builtin_amdgcn_mfma_f32_16x16x32_f16(
                    v1, pf[qg][1].v, o_acc[qg][t], 0, 0, 0);
            }
        }
    }

    // ---- epilogue: l = full sum (per-lane partials over g), O/l -> ctx ----
#pragma unroll
    for (int qg = 0; qg < 2; ++qg) {
        float lt = l_s[qg];
        lt += __shfl_xor(lt, 16);
        lt += __shfl_xor(lt, 32);
        float inv = 1.f / lt;
        size_t rowbase =
            ((size_t)(b * S_ + q0 + w * 32 + qg * 16 + c)) * 1024 + rh * 64;
#pragma unroll
        for (int t = 0; t < 4; ++t) {
            union { half4 v; fp16x2 h2[2]; } e;
            e.h2[0] = __builtin_amdgcn_cvt_pkrtz(o_acc[qg][t][0] * inv,
                                                 o_acc[qg][t][1] * inv);
            e.h2[1] = __builtin_amdgcn_cvt_pkrtz(o_acc[qg][t][2] * inv,
                                                 o_acc[qg][t][3] * inv);
            *(half4*)(ctx + rowbase + 16 * t + 4 * g) = e.v;
        }
    }
}

// --------------------- LayerNorm in place on y[4096][1024] -----------------
__global__ __launch_bounds__(256) void ln_kernel(
    float* __restrict__ y, const float* __restrict__ g, const float* __restrict__ bb)
{
    int row = blockIdx.x, tid = threadIdx.x;
    float* p = y + (size_t)row * 1024;
    float4 v = ((const float4*)p)[tid];
    float sum = v.x + v.y + v.z + v.w;
    float sq  = v.x*v.x + v.y*v.y + v.z*v.z + v.w*v.w;
#pragma unroll
    for (int off = 32; off > 0; off >>= 1) {
        sum += __shfl_xor(sum, off);
        sq  += __shfl_xor(sq,  off);
    }
    __shared__ float rs[4], rq[4];
    int w = tid >> 6;
    if ((tid & 63) == 0) { rs[w] = sum; rq[w] = sq; }
    __syncthreads();
    sum = rs[0] + rs[1] + rs[2] + rs[3];
    sq  = rq[0] + rq[1] + rq[2] + rq[3];
    float mean = sum * (1.f / 1024.f);
    float var  = sq * (1.f / 1024.f) - mean * mean;
    float inv  = rsqrtf(var + 1e-5f);
    float4 gv = ((const float4*)g)[tid];
    float4 bv = ((const float4*)bb)[tid];
    v.x = (v.x - mean) * inv * gv.x + bv.x;
    v.y = (v.y - mean) * inv * gv.y + bv.y;
    v.z = (v.z - mean) * inv * gv.z + bv.z;
    v.w = (v.w - mean) * inv * gv.w + bv.w;
    ((float4*)p)[tid] = v;
}

// ---------------------------------------------------------------------------
extern "C" void kernel_launch(void* const* d_in, const int* in_sizes, int n_in,
                              void* d_out, int out_size, void* d_ws, size_t ws_size,
                              hipStream_t stream)
{
    const float* x     = (const float*)d_in[0];
    const float* pos   = (const float*)d_in[1];
    const float* W_qkv = (const float*)d_in[2];
    const float* b_qkv = (const float*)d_in[3];
    const float* W_out = (const float*)d_in[4];
    const float* b_out = (const float*)d_in[5];
    const float* ln_g  = (const float*)d_in[6];
    const float* ln_b  = (const float*)d_in[7];
    float* out = (float*)d_out;

    // workspace layout (72 MB)
    char* ws = (char*)d_ws;
    _Float16* x_h    = (_Float16*)(ws);                       //  8 MB
    _Float16* wqkv_t = (_Float16*)(ws + ((size_t)8  << 20));  //  6 MB
    _Float16* wout_t = (_Float16*)(ws + ((size_t)14 << 20));  //  2 MB
    _Float16* qkvh   = (_Float16*)(ws + ((size_t)16 << 20));  // 24 MB (f16)
    _Float16* qt_h   = (_Float16*)(ws + ((size_t)40 << 20));  //  8 MB
    _Float16* kt_h   = (_Float16*)(ws + ((size_t)48 << 20));  //  8 MB
    _Float16* vt2_h  = (_Float16*)(ws + ((size_t)56 << 20));  //  8 MB
    _Float16* ctx_h  = (_Float16*)(ws + ((size_t)64 << 20));  //  8 MB

    // 1) fused cast + weight transposes
    prep0_kernel<<<8192, 256, 0, stream>>>(x, x_h, W_qkv, wqkv_t, W_out, wout_t);

    // 2) qkv (f16) = x @ W_qkv + b_qkv
    gemm_f16_mfma<true><<<dim3(NQKV / 128, BS_ / 128), 256, 0, stream>>>(
        x_h, wqkv_t, b_qkv, nullptr, nullptr, qkvh, BS_, NQKV, H_);

    // 3) fused k-norm + RoPE + V-image
    prep1_kernel<<<dim3(32, 32), 256, 0, stream>>>(qkvh, pos, qt_h, kt_h, vt2_h);

    // 4) MFMA flash attention -> ctx f16
    attn_mfma_kernel<<<dim3(32, 16), 256, 0, stream>>>(qt_h, kt_h, vt2_h, ctx_h);

    // 5) out (fp32) = x + ctx @ W_out + b_out
    gemm_f16_mfma<false><<<dim3(H_ / 128, BS_ / 128), 256, 0, stream>>>(
        ctx_h, wout_t, b_out, x, out, nullptr, BS_, H_, H_);

    // 6) LayerNorm in place
    ln_kernel<<<BS_, 256, 0, stream>>>(out, ln_g, ln_b);
}

// Round 9
// 228.735 us; speedup vs baseline: 1.1297x; 1.0031x over previous
//
#include <hip/hip_runtime.h>

// ---------------------------------------------------------------------------
// SelfMultiHeadAttn: x[B,S,H] -> LN(x + OutProj(SDPA(RoPE(q), RoPE(k/|k|), v)))
// B=2 S=2048 H=1024 R=16 heads, K=64 head dim. fp32 in/out.
// R9 = R8 structure, attn reverted to R7 softmax (plain exp2f, VGPR 72) +
//      K/V LDS ping-pong double-buffer: ONE barrier per tile, prefetch issued
//      post-barrier flies during compute -> staging latency hidden.
// ---------------------------------------------------------------------------

#define B_   2
#define S_   2048
#define H_   1024
#define R_   16
#define BS_  (B_*S_)     // 4096 rows
#define NQKV 3072        // R*K*3
#define LOG2E 1.44269504088896f

typedef float    floatx4 __attribute__((ext_vector_type(4)));
typedef _Float16 half8   __attribute__((ext_vector_type(8)));
typedef _Float16 half4   __attribute__((ext_vector_type(4)));
typedef __fp16   fp16x2  __attribute__((ext_vector_type(2)));  // cvt_pkrtz ret

#if __has_builtin(__builtin_amdgcn_exp2f)
#define EXP2(x) __builtin_amdgcn_exp2f(x)
#else
#define EXP2(x) exp2f(x)
#endif

// async global -> LDS, 16 B per lane (lds dest = wave-uniform base + lane*16)
__device__ __forceinline__ void gl_lds16(const _Float16* g, _Float16* l) {
    __builtin_amdgcn_global_load_lds(
        (const __attribute__((address_space(1))) unsigned int*)g,
        (__attribute__((address_space(3))) unsigned int*)l, 16, 0, 0);
}

// ------- fused preprocessing: x cast + W_qkv^T + W_out^T (one launch) ------
// grid 8192: [0,4096) cast x; [4096,7168) W_qkv transpose; [7168,8192) W_out.
__global__ __launch_bounds__(256) void prep0_kernel(
    const float* __restrict__ x, _Float16* __restrict__ x_h,
    const float* __restrict__ W_qkv, _Float16* __restrict__ wqkv_t,
    const float* __restrict__ W_out, _Float16* __restrict__ wout_t)
{
    __shared__ float tile[32][33];
    int bid = blockIdx.x, tid = threadIdx.x;
    if (bid < 4096) {
        int i = bid * 1024 + tid * 4;
        float4 v = *(const float4*)(x + i);
        half4 h;
        h.x = (_Float16)v.x; h.y = (_Float16)v.y;
        h.z = (_Float16)v.z; h.w = (_Float16)v.w;
        *(half4*)(x_h + i) = h;
        return;
    }
    const float* in; _Float16* out; int rows, cols, bx, by;
    if (bid < 7168) {
        int t = bid - 4096;
        in = W_qkv; out = wqkv_t; rows = H_; cols = NQKV;
        bx = t % 96; by = t / 96;
    } else {
        int t = bid - 7168;
        in = W_out; out = wout_t; rows = H_; cols = H_;
        bx = t & 31; by = t >> 5;
    }
    int cx = bx * 32, ry = by * 32;
    int tx = tid & 31, ty = tid >> 5;   // ty 0..7
#pragma unroll
    for (int i = 0; i < 32; i += 8)
        tile[ty + i][tx] = in[(size_t)(ry + ty + i) * cols + cx + tx];
    __syncthreads();
#pragma unroll
    for (int i = 0; i < 32; i += 8)
        out[(size_t)(cx + ty + i) * rows + ry + tx] = (_Float16)tile[tx][ty + i];
}

// ---------- f16 MFMA GEMM, K-loop double-buffered:  C = A @ Bt^T + bias ----
// F16OUT=true: write f16 to Ch (no resid). F16OUT=false: fp32 +resid to Cf.
//   A: lane holds A[m=lane&15][k = 8*(lane>>4) + j]
//   B: lane holds B[k = 8*(lane>>4) + j][n=lane&15]   (reads Bt[n][k] contig)
//   D: reg r holds D[row = 4*(lane>>4) + r][col = lane&15]
template <bool F16OUT>
__global__ __launch_bounds__(256) void gemm_f16_mfma(
    const _Float16* __restrict__ A, const _Float16* __restrict__ Bt,
    const float* __restrict__ bias, const float* __restrict__ resid,
    float* __restrict__ Cf, _Float16* __restrict__ Ch, int M, int N, int Kd)
{
    __shared__ _Float16 Als[2][4096];
    __shared__ _Float16 Bls[2][4096];
    int tid  = threadIdx.x;
    int lane = tid & 63, w = tid >> 6;
    int wr = w >> 1, wc = w & 1;
    int fr = lane & 15, fq = lane >> 4;
    int m0 = blockIdx.y * 128, n0 = blockIdx.x * 128;

    floatx4 acc[4][4] = {};

    const _Float16* ga[2]; const _Float16* gb[2];
    int loff[2];
#pragma unroll
    for (int i2 = 0; i2 < 2; ++i2) {
        int ch = 2 * w + i2;
        int row = ch * 16 + (lane >> 2), col = (lane & 3) * 8;
        ga[i2] = A  + (size_t)(m0 + row) * Kd + col;
        gb[i2] = Bt + (size_t)(n0 + row) * Kd + col;
        loff[i2] = ch * 512;
    }

    int nIter = Kd >> 5;
#pragma unroll
    for (int i2 = 0; i2 < 2; ++i2) {
        gl_lds16(ga[i2], &Als[0][loff[i2]]);
        gl_lds16(gb[i2], &Bls[0][loff[i2]]);
    }

    for (int it = 0; it < nIter; ++it) {
        int cur = it & 1;
        __syncthreads();               // buf[cur] staged; buf[cur^1] free
        if (it + 1 < nIter) {
            int k1 = (it + 1) << 5;
#pragma unroll
            for (int i2 = 0; i2 < 2; ++i2) {
                gl_lds16(ga[i2] + k1, &Als[cur ^ 1][loff[i2]]);
                gl_lds16(gb[i2] + k1, &Bls[cur ^ 1][loff[i2]]);
            }
        }
        const _Float16* Ab = Als[cur];
        const _Float16* Bb = Bls[cur];
        half8 af[4], bf[4];
#pragma unroll
        for (int i = 0; i < 4; ++i)
            af[i] = *(const half8*)(Ab + (wr * 64 + i * 16 + fr) * 32 + fq * 8);
#pragma unroll
        for (int j = 0; j < 4; ++j)
            bf[j] = *(const half8*)(Bb + (wc * 64 + j * 16 + fr) * 32 + fq * 8);
#pragma unroll
        for (int i = 0; i < 4; ++i)
#pragma unroll
            for (int j = 0; j < 4; ++j)
                acc[i][j] = __builtin_amdgcn_mfma_f32_16x16x32_f16(
                    af[i], bf[j], acc[i][j], 0, 0, 0);
    }

#pragma unroll
    for (int i = 0; i < 4; ++i)
#pragma unroll
        for (int j = 0; j < 4; ++j)
#pragma unroll
            for (int r2 = 0; r2 < 4; ++r2) {
                int row = m0 + wr * 64 + i * 16 + fq * 4 + r2;
                int col = n0 + wc * 64 + j * 16 + fr;
                float v = acc[i][j][r2] + bias[col];
                if constexpr (F16OUT) {
                    Ch[(size_t)row * N + col] = (_Float16)v;
                } else {
                    if (resid) v += resid[(size_t)row * N + col];
                    Cf[(size_t)row * N + col] = v;
                }
            }
}

// ------- fused prep1: k-norm + RoPE -> qt/kt f16; V -> vt2 LDS image -------
// grid (head 32, s-tile 32), block 256 = 4 waves.
// vt2[head][tau][d][P]: position P of row d holds V[key_of(P,d)][d] with
// op=P>>3, ol=op^(d&7): key_of = 32*(ol>>2)+16*((P>>2)&1)+4*(ol&3)+(P&3)
// (bakes PV keymap + bank XOR swizzle). q~ pre-scaled by LOG2E.
__global__ __launch_bounds__(256) void prep1_kernel(
    const _Float16* __restrict__ qkvh, const float* __restrict__ pos,
    _Float16* __restrict__ qt, _Float16* __restrict__ kt,
    _Float16* __restrict__ vt2)
{
    __shared__ float tile[64][65];
    int head = blockIdx.x, tau = blockIdx.y;
    int s0 = tau * 64;
    int b = head >> 4, rh = head & 15;
    int lane = threadIdx.x & 63, w = threadIdx.x >> 6;

    // ---- V slice -> LDS -> permuted image ----
#pragma unroll
    for (int si = w; si < 64; si += 4)
        tile[si][lane] =
            (float)qkvh[(size_t)(b * S_ + s0 + si) * NQKV + rh * 192 + 128 + lane];
    __syncthreads();
    {
        int P = lane;
        int op = P >> 3;
        int hi = (P >> 2) & 1, lo = P & 3;
#pragma unroll
        for (int d = w; d < 64; d += 4) {
            int ol = op ^ (d & 7);
            int key = 32 * (ol >> 2) + 16 * hi + 4 * (ol & 3) + lo;
            vt2[(((size_t)head * 32 + tau) * 64 + d) * 64 + P] = (_Float16)tile[key][d];
        }
    }

    // ---- RoPE + k-norm: wave w handles rows s0 + w*16 + i ----
    for (int i = 0; i < 16; ++i) {
        int s = s0 + w * 16 + i;
        int bs = b * S_ + s;
        const _Float16* base = qkvh + (size_t)bs * NQKV + rh * 192;
        float qv = (float)base[lane];
        float kv = (float)base[64 + lane];

        float ss = kv * kv;
#pragma unroll
        for (int off = 32; off > 0; off >>= 1) ss += __shfl_xor(ss, off);
        kv *= rsqrtf(ss);

        int j = lane & 31;
        float sn = pos[(size_t)bs * 64 + j];
        float cs = pos[(size_t)bs * 64 + 32 + j];
        float qp = __shfl_xor(qv, 32);
        float kp = __shfl_xor(kv, 32);
        float qo, ko;
        if (lane < 32) { qo = qv * cs - qp * sn; ko = kv * cs - kp * sn; }
        else           { qo = qp * sn + qv * cs; ko = kp * sn + kv * cs; }

        size_t oidx = ((size_t)head * S_ + s) * 64 + lane;
        qt[oidx] = (_Float16)(qo * LOG2E);   // fold log2(e) into q~
        kt[oidx] = (_Float16)ko;
    }
}

// ------------- transposed MFMA flash attention, K/V double-buffer ----------
// grid (32 heads, 16 q-tiles of 128), block 256 = 4 waves; wave w owns 32
// queries as 2 q-groups of 16 (one query per lane-column c). Per 64-key tile:
//   ONE barrier; prefetch tile jt+1 into buf^1 (flies during compute);
//   kfr = K frags (8 ds_read_b128, shared by both q-groups)
//   S^T = K @ Q~^T (log2-scaled), p = exp2(s - |q~|) (static max), l partial
//   V frags shared; O^T += V^T @ P^T
__global__ __launch_bounds__(256) void attn_mfma_kernel(
    const _Float16* __restrict__ qt, const _Float16* __restrict__ kt,
    const _Float16* __restrict__ vt2, _Float16* __restrict__ ctx)
{
    __shared__ _Float16 Kls[2][4096];
    __shared__ _Float16 Vls[2][4096];

    int head = blockIdx.x, q0 = blockIdx.y * 128;
    int b = head >> 4, rh = head & 15;
    int tid = threadIdx.x, lane = tid & 63, w = tid >> 6;
    int g = lane >> 4, c = lane & 15;

    // Q B-frags + static softmax bound mL = |q~| (log2 units) per q-group
    half8 qf[2][2];
    float mL[2], l_s[2] = {0.f, 0.f};
#pragma unroll
    for (int qg = 0; qg < 2; ++qg) {
        const _Float16* qp =
            qt + ((size_t)head * S_ + q0 + w * 32 + qg * 16 + c) * 64 + 8 * g;
        qf[qg][0] = *(const half8*)qp;
        qf[qg][1] = *(const half8*)(qp + 32);
        float qq = 0.f;
#pragma unroll
        for (int i = 0; i < 8; ++i) {
            float a = (float)qf[qg][0][i], b2 = (float)qf[qg][1][i];
            qq += a * a + b2 * b2;
        }
        qq += __shfl_xor(qq, 16);
        qq += __shfl_xor(qq, 32);
        mL[qg] = sqrtf(qq);       // s_log2 <= |q~|*|k^| = mL  (k^ unit norm)
    }

    floatx4 o_acc[2][4] = {};

    // staging geometry (per wave: K chunks {2w,2w+1}, V chunks {2w,2w+1}).
    // K: lane L -> row ch*8+(L>>3), d-octet (L&7)^(L>>3)  (XOR swizzle via
    // global source address). V: vt2 is already the LDS image -> linear copy.
    const _Float16* kg[2]; const _Float16* vg[2];
    int loff[2];
#pragma unroll
    for (int i2 = 0; i2 < 2; ++i2) {
        int ch = 2 * w + i2;
        int krow = ch * 8 + (lane >> 3);
        int koct = (lane & 7) ^ (lane >> 3);
        kg[i2] = kt + ((size_t)head * S_ + krow) * 64 + koct * 8;
        vg[i2] = vt2 + ((size_t)head * 32) * 4096 + ch * 512 + lane * 8;
        loff[i2] = ch * 512;
    }

    int co = c & 7;   // XOR swizzle term for frag reads

    // prologue: stage tile 0 into buffer 0
#pragma unroll
    for (int i2 = 0; i2 < 2; ++i2) {
        gl_lds16(kg[i2], &Kls[0][loff[i2]]);
        gl_lds16(vg[i2], &Vls[0][loff[i2]]);
    }

    for (int jt = 0; jt < 32; ++jt) {
        int cur = jt & 1;
        __syncthreads();       // buf[cur] staged (vmcnt drained); buf[cur^1] free
        if (jt + 1 < 32) {     // prefetch tile jt+1 -> flies during compute
#pragma unroll
            for (int i2 = 0; i2 < 2; ++i2) {
                gl_lds16(kg[i2] + (size_t)(jt + 1) * 4096, &Kls[cur ^ 1][loff[i2]]);
                gl_lds16(vg[i2] + (size_t)(jt + 1) * 4096, &Vls[cur ^ 1][loff[i2]]);
            }
        }
        const _Float16* Kbuf = Kls[cur];
        const _Float16* Vbuf = Vls[cur];

        // ---- K fragments once, shared by both q-groups ----
        half8 kfr[8];
#pragma unroll
        for (int t = 0; t < 4; ++t) {
            const _Float16* krow = Kbuf + (16 * t + c) * 64;
            kfr[2 * t]     = *(const half8*)(krow + ((g) ^ co) * 8);
            kfr[2 * t + 1] = *(const half8*)(krow + ((4 + g) ^ co) * 8);
        }

        union { half8 v; fp16x2 h2[4]; } pf[2][2];
#pragma unroll
        for (int qg = 0; qg < 2; ++qg) {
            // S^T = K @ Q~^T  (result already in log2 units)
            floatx4 sacc[4];
#pragma unroll
            for (int t = 0; t < 4; ++t) {
                floatx4 z = {};
                z = __builtin_amdgcn_mfma_f32_16x16x32_f16(
                    kfr[2 * t], qf[qg][0], z, 0, 0, 0);
                z = __builtin_amdgcn_mfma_f32_16x16x32_f16(
                    kfr[2 * t + 1], qf[qg][1], z, 0, 0, 0);
                sacc[t] = z;
            }
            // static-max softmax: p = exp2(s - mL); l accumulates per-lane
            float mLq = mL[qg], ps = 0.f;
#pragma unroll
            for (int t = 0; t < 4; ++t)
#pragma unroll
                for (int r = 0; r < 4; ++r) {
                    float p = EXP2(sacc[t][r] - mLq);
                    sacc[t][r] = p;
                    ps += p;
                }
            l_s[qg] += ps;
            pf[qg][0].h2[0] = __builtin_amdgcn_cvt_pkrtz(sacc[0][0], sacc[0][1]);
            pf[qg][0].h2[1] = __builtin_amdgcn_cvt_pkrtz(sacc[0][2], sacc[0][3]);
            pf[qg][0].h2[2] = __builtin_amdgcn_cvt_pkrtz(sacc[1][0], sacc[1][1]);
            pf[qg][0].h2[3] = __builtin_amdgcn_cvt_pkrtz(sacc[1][2], sacc[1][3]);
            pf[qg][1].h2[0] = __builtin_amdgcn_cvt_pkrtz(sacc[2][0], sacc[2][1]);
            pf[qg][1].h2[1] = __builtin_amdgcn_cvt_pkrtz(sacc[2][2], sacc[2][3]);
            pf[qg][1].h2[2] = __builtin_amdgcn_cvt_pkrtz(sacc[3][0], sacc[3][1]);
            pf[qg][1].h2[3] = __builtin_amdgcn_cvt_pkrtz(sacc[3][2], sacc[3][3]);
        }

        // ---- V fragments once, shared; O^T += V^T @ P^T ----
#pragma unroll
        for (int t = 0; t < 4; ++t) {
            const _Float16* vrow = Vbuf + (16 * t + c) * 64;
            half8 v0 = *(const half8*)(vrow + ((g) ^ co) * 8);
            half8 v1 = *(const half8*)(vrow + ((4 + g) ^ co) * 8);
#pragma unroll
            for (int qg = 0; qg < 2; ++qg) {
                o_acc[qg][t] = __builtin_amdgcn_mfma_f32_16x16x32_f16(
                    v0, pf[qg][0].v, o_acc[qg][t], 0, 0, 0);
                o_acc[qg][t] = __builtin_amdgcn_mfma_f32_16x16x32_f16(
                    v1, pf[qg][1].v, o_acc[qg][t], 0, 0, 0);
            }
        }
    }

    // ---- epilogue: l = full sum (per-lane partials over g), O/l -> ctx ----
#pragma unroll
    for (int qg = 0; qg < 2; ++qg) {
        float lt = l_s[qg];
        lt += __shfl_xor(lt, 16);
        lt += __shfl_xor(lt, 32);
        float inv = 1.f / lt;
        size_t rowbase =
            ((size_t)(b * S_ + q0 + w * 32 + qg * 16 + c)) * 1024 + rh * 64;
#pragma unroll
        for (int t = 0; t < 4; ++t) {
            union { half4 v; fp16x2 h2[2]; } e;
            e.h2[0] = __builtin_amdgcn_cvt_pkrtz(o_acc[qg][t][0] * inv,
                                                 o_acc[qg][t][1] * inv);
            e.h2[1] = __builtin_amdgcn_cvt_pkrtz(o_acc[qg][t][2] * inv,
                                                 o_acc[qg][t][3] * inv);
            *(half4*)(ctx + rowbase + 16 * t + 4 * g) = e.v;
        }
    }
}

// --------------------- LayerNorm in place on y[4096][1024] -----------------
__global__ __launch_bounds__(256) void ln_kernel(
    float* __restrict__ y, const float* __restrict__ g, const float* __restrict__ bb)
{
    int row = blockIdx.x, tid = threadIdx.x;
    float* p = y + (size_t)row * 1024;
    float4 v = ((const float4*)p)[tid];
    float sum = v.x + v.y + v.z + v.w;
    float sq  = v.x*v.x + v.y*v.y + v.z*v.z + v.w*v.w;
#pragma unroll
    for (int off = 32; off > 0; off >>= 1) {
        sum += __shfl_xor(sum, off);
        sq  += __shfl_xor(sq,  off);
    }
    __shared__ float rs[4], rq[4];
    int w = tid >> 6;
    if ((tid & 63) == 0) { rs[w] = sum; rq[w] = sq; }
    __syncthreads();
    sum = rs[0] + rs[1] + rs[2] + rs[3];
    sq  = rq[0] + rq[1] + rq[2] + rq[3];
    float mean = sum * (1.f / 1024.f);
    float var  = sq * (1.f / 1024.f) - mean * mean;
    float inv  = rsqrtf(var + 1e-5f);
    float4 gv = ((const float4*)g)[tid];
    float4 bv = ((const float4*)bb)[tid];
    v.x = (v.x - mean) * inv * gv.x + bv.x;
    v.y = (v.y - mean) * inv * gv.y + bv.y;
    v.z = (v.z - mean) * inv * gv.z + bv.z;
    v.w = (v.w - mean) * inv * gv.w + bv.w;
    ((float4*)p)[tid] = v;
}

// ---------------------------------------------------------------------------
extern "C" void kernel_launch(void* const* d_in, const int* in_sizes, int n_in,
                              void* d_out, int out_size, void* d_ws, size_t ws_size,
                              hipStream_t stream)
{
    const float* x     = (const float*)d_in[0];
    const float* pos   = (const float*)d_in[1];
    const float* W_qkv = (const float*)d_in[2];
    const float* b_qkv = (const float*)d_in[3];
    const float* W_out = (const float*)d_in[4];
    const float* b_out = (const float*)d_in[5];
    const float* ln_g  = (const float*)d_in[6];
    const float* ln_b  = (const float*)d_in[7];
    float* out = (float*)d_out;

    // workspace layout (72 MB)
    char* ws = (char*)d_ws;
    _Float16* x_h    = (_Float16*)(ws);                       //  8 MB
    _Float16* wqkv_t = (_Float16*)(ws + ((size_t)8  << 20));  //  6 MB
    _Float16* wout_t = (_Float16*)(ws + ((size_t)14 << 20));  //  2 MB
    _Float16* qkvh   = (_Float16*)(ws + ((size_t)16 << 20));  // 24 MB (f16)
    _Float16* qt_h   = (_Float16*)(ws + ((size_t)40 << 20));  //  8 MB
    _Float16* kt_h   = (_Float16*)(ws + ((size_t)48 << 20));  //  8 MB
    _Float16* vt2_h  = (_Float16*)(ws + ((size_t)56 << 20));  //  8 MB
    _Float16* ctx_h  = (_Float16*)(ws + ((size_t)64 << 20));  //  8 MB

    // 1) fused cast + weight transposes
    prep0_kernel<<<8192, 256, 0, stream>>>(x, x_h, W_qkv, wqkv_t, W_out, wout_t);

    // 2) qkv (f16) = x @ W_qkv + b_qkv
    gemm_f16_mfma<true><<<dim3(NQKV / 128, BS_ / 128), 256, 0, stream>>>(
        x_h, wqkv_t, b_qkv, nullptr, nullptr, qkvh, BS_, NQKV, H_);

    // 3) fused k-norm + RoPE + V-image
    prep1_kernel<<<dim3(32, 32), 256, 0, stream>>>(qkvh, pos, qt_h, kt_h, vt2_h);

    // 4) MFMA flash attention (double-buffered) -> ctx f16
    attn_mfma_kernel<<<dim3(32, 16), 256, 0, stream>>>(qt_h, kt_h, vt2_h, ctx_h);

    // 5) out (fp32) = x + ctx @ W_out + b_out
    gemm_f16_mfma<false><<<dim3(H_ / 128, BS_ / 128), 256, 0, stream>>>(
        ctx_h, wout_t, b_out, x, out, nullptr, BS_, H_, H_);

    // 6) LayerNorm in place
    ln_kernel<<<BS_, 256, 0, stream>>>(out, ln_g, ln_b);
}

// Round 10
// 223.880 us; speedup vs baseline: 1.1542x; 1.0217x over previous
//
#include <hip/hip_runtime.h>

// ---------------------------------------------------------------------------
// SelfMultiHeadAttn: x[B,S,H] -> LN(x + OutProj(SDPA(RoPE(q), RoPE(k/|k|), v)))
// B=2 S=2048 H=1024 R=16 heads, K=64 head dim. fp32 in/out.
// R10 = R9 + (1) attn key-split x2 (static-max softmax => partials are
//       exactly additive; tiny merge kernel) -> 4 blocks/CU;
//       (2) out-proj GEMM 64x64 tile -> 4 blocks/CU (was 1).
// ---------------------------------------------------------------------------

#define B_   2
#define S_   2048
#define H_   1024
#define R_   16
#define BS_  (B_*S_)     // 4096 rows
#define NQKV 3072        // R*K*3
#define LOG2E 1.44269504088896f

typedef float    floatx4 __attribute__((ext_vector_type(4)));
typedef _Float16 half8   __attribute__((ext_vector_type(8)));
typedef _Float16 half4   __attribute__((ext_vector_type(4)));
typedef __fp16   fp16x2  __attribute__((ext_vector_type(2)));  // cvt_pkrtz ret

#if __has_builtin(__builtin_amdgcn_exp2f)
#define EXP2(x) __builtin_amdgcn_exp2f(x)
#else
#define EXP2(x) exp2f(x)
#endif

// async global -> LDS, 16 B per lane (lds dest = wave-uniform base + lane*16)
__device__ __forceinline__ void gl_lds16(const _Float16* g, _Float16* l) {
    __builtin_amdgcn_global_load_lds(
        (const __attribute__((address_space(1))) unsigned int*)g,
        (__attribute__((address_space(3))) unsigned int*)l, 16, 0, 0);
}

// ------- fused preprocessing: x cast + W_qkv^T + W_out^T (one launch) ------
// grid 8192: [0,4096) cast x; [4096,7168) W_qkv transpose; [7168,8192) W_out.
__global__ __launch_bounds__(256) void prep0_kernel(
    const float* __restrict__ x, _Float16* __restrict__ x_h,
    const float* __restrict__ W_qkv, _Float16* __restrict__ wqkv_t,
    const float* __restrict__ W_out, _Float16* __restrict__ wout_t)
{
    __shared__ float tile[32][33];
    int bid = blockIdx.x, tid = threadIdx.x;
    if (bid < 4096) {
        int i = bid * 1024 + tid * 4;
        float4 v = *(const float4*)(x + i);
        half4 h;
        h.x = (_Float16)v.x; h.y = (_Float16)v.y;
        h.z = (_Float16)v.z; h.w = (_Float16)v.w;
        *(half4*)(x_h + i) = h;
        return;
    }
    const float* in; _Float16* out; int rows, cols, bx, by;
    if (bid < 7168) {
        int t = bid - 4096;
        in = W_qkv; out = wqkv_t; rows = H_; cols = NQKV;
        bx = t % 96; by = t / 96;
    } else {
        int t = bid - 7168;
        in = W_out; out = wout_t; rows = H_; cols = H_;
        bx = t & 31; by = t >> 5;
    }
    int cx = bx * 32, ry = by * 32;
    int tx = tid & 31, ty = tid >> 5;   // ty 0..7
#pragma unroll
    for (int i = 0; i < 32; i += 8)
        tile[ty + i][tx] = in[(size_t)(ry + ty + i) * cols + cx + tx];
    __syncthreads();
#pragma unroll
    for (int i = 0; i < 32; i += 8)
        out[(size_t)(cx + ty + i) * rows + ry + tx] = (_Float16)tile[tx][ty + i];
}

// ---------- f16 MFMA GEMM 128x128, dbuf:  Ch(f16) = A @ Bt^T + bias --------
//   A: lane holds A[m=lane&15][k = 8*(lane>>4) + j]
//   B: lane holds B[k = 8*(lane>>4) + j][n=lane&15]   (reads Bt[n][k] contig)
//   D: reg r holds D[row = 4*(lane>>4) + r][col = lane&15]
__global__ __launch_bounds__(256) void gemm_f16_mfma(
    const _Float16* __restrict__ A, const _Float16* __restrict__ Bt,
    const float* __restrict__ bias, _Float16* __restrict__ Ch,
    int M, int N, int Kd)
{
    __shared__ _Float16 Als[2][4096];
    __shared__ _Float16 Bls[2][4096];
    int tid  = threadIdx.x;
    int lane = tid & 63, w = tid >> 6;
    int wr = w >> 1, wc = w & 1;
    int fr = lane & 15, fq = lane >> 4;
    int m0 = blockIdx.y * 128, n0 = blockIdx.x * 128;

    floatx4 acc[4][4] = {};

    const _Float16* ga[2]; const _Float16* gb[2];
    int loff[2];
#pragma unroll
    for (int i2 = 0; i2 < 2; ++i2) {
        int ch = 2 * w + i2;
        int row = ch * 16 + (lane >> 2), col = (lane & 3) * 8;
        ga[i2] = A  + (size_t)(m0 + row) * Kd + col;
        gb[i2] = Bt + (size_t)(n0 + row) * Kd + col;
        loff[i2] = ch * 512;
    }

    int nIter = Kd >> 5;
#pragma unroll
    for (int i2 = 0; i2 < 2; ++i2) {
        gl_lds16(ga[i2], &Als[0][loff[i2]]);
        gl_lds16(gb[i2], &Bls[0][loff[i2]]);
    }

    for (int it = 0; it < nIter; ++it) {
        int cur = it & 1;
        __syncthreads();               // buf[cur] staged; buf[cur^1] free
        if (it + 1 < nIter) {
            int k1 = (it + 1) << 5;
#pragma unroll
            for (int i2 = 0; i2 < 2; ++i2) {
                gl_lds16(ga[i2] + k1, &Als[cur ^ 1][loff[i2]]);
                gl_lds16(gb[i2] + k1, &Bls[cur ^ 1][loff[i2]]);
            }
        }
        const _Float16* Ab = Als[cur];
        const _Float16* Bb = Bls[cur];
        half8 af[4], bf[4];
#pragma unroll
        for (int i = 0; i < 4; ++i)
            af[i] = *(const half8*)(Ab + (wr * 64 + i * 16 + fr) * 32 + fq * 8);
#pragma unroll
        for (int j = 0; j < 4; ++j)
            bf[j] = *(const half8*)(Bb + (wc * 64 + j * 16 + fr) * 32 + fq * 8);
#pragma unroll
        for (int i = 0; i < 4; ++i)
#pragma unroll
            for (int j = 0; j < 4; ++j)
                acc[i][j] = __builtin_amdgcn_mfma_f32_16x16x32_f16(
                    af[i], bf[j], acc[i][j], 0, 0, 0);
    }

#pragma unroll
    for (int i = 0; i < 4; ++i)
#pragma unroll
        for (int j = 0; j < 4; ++j)
#pragma unroll
            for (int r2 = 0; r2 < 4; ++r2) {
                int row = m0 + wr * 64 + i * 16 + fq * 4 + r2;
                int col = n0 + wc * 64 + j * 16 + fr;
                Ch[(size_t)row * N + col] = (_Float16)(acc[i][j][r2] + bias[col]);
            }
}

// ---------- f16 MFMA GEMM 64x64, dbuf: Cf(f32) = A@Bt^T + bias + resid -----
// 4 waves, each 32x32 (2x2 frags). grid (N/64, M/64) -> 4 blocks/CU for
// the out-projection (was 1 block/CU at 128-tile).
__global__ __launch_bounds__(256) void gemm64_f16_mfma(
    const _Float16* __restrict__ A, const _Float16* __restrict__ Bt,
    const float* __restrict__ bias, const float* __restrict__ resid,
    float* __restrict__ Cf, int M, int N, int Kd)
{
    __shared__ _Float16 Als[2][2048];
    __shared__ _Float16 Bls[2][2048];
    int tid = threadIdx.x, lane = tid & 63, w = tid >> 6;
    int wr = w >> 1, wc = w & 1;
    int fr = lane & 15, fq = lane >> 4;
    int m0 = blockIdx.y * 64, n0 = blockIdx.x * 64;

    floatx4 acc[2][2] = {};

    // staging: wave w stages rows [w*16, w*16+16) of A and B (1KB each):
    // lane L -> row w*16+(L>>2), col (L&3)*8; LDS offset w*512 + L*8.
    int srow = w * 16 + (lane >> 2), scol = (lane & 3) * 8;
    const _Float16* ga = A  + (size_t)(m0 + srow) * Kd + scol;
    const _Float16* gb = Bt + (size_t)(n0 + srow) * Kd + scol;
    int loff = w * 512;

    int nIter = Kd >> 5;
    gl_lds16(ga, &Als[0][loff]);
    gl_lds16(gb, &Bls[0][loff]);

    for (int it = 0; it < nIter; ++it) {
        int cur = it & 1;
        __syncthreads();
        if (it + 1 < nIter) {
            int k1 = (it + 1) << 5;
            gl_lds16(ga + k1, &Als[cur ^ 1][loff]);
            gl_lds16(gb + k1, &Bls[cur ^ 1][loff]);
        }
        const _Float16* Ab = Als[cur];
        const _Float16* Bb = Bls[cur];
        half8 af[2], bf[2];
#pragma unroll
        for (int i = 0; i < 2; ++i)
            af[i] = *(const half8*)(Ab + (wr * 32 + i * 16 + fr) * 32 + fq * 8);
#pragma unroll
        for (int j = 0; j < 2; ++j)
            bf[j] = *(const half8*)(Bb + (wc * 32 + j * 16 + fr) * 32 + fq * 8);
#pragma unroll
        for (int i = 0; i < 2; ++i)
#pragma unroll
            for (int j = 0; j < 2; ++j)
                acc[i][j] = __builtin_amdgcn_mfma_f32_16x16x32_f16(
                    af[i], bf[j], acc[i][j], 0, 0, 0);
    }

#pragma unroll
    for (int i = 0; i < 2; ++i)
#pragma unroll
        for (int j = 0; j < 2; ++j)
#pragma unroll
            for (int r2 = 0; r2 < 4; ++r2) {
                int row = m0 + wr * 32 + i * 16 + fq * 4 + r2;
                int col = n0 + wc * 32 + j * 16 + fr;
                Cf[(size_t)row * N + col] =
                    acc[i][j][r2] + bias[col] + resid[(size_t)row * N + col];
            }
}

// ------- fused prep1: k-norm + RoPE -> qt/kt f16; V -> vt2 LDS image -------
// grid (head 32, s-tile 32), block 256 = 4 waves.
// vt2[head][tau][d][P]: position P of row d holds V[key_of(P,d)][d] with
// op=P>>3, ol=op^(d&7): key_of = 32*(ol>>2)+16*((P>>2)&1)+4*(ol&3)+(P&3)
// (bakes PV keymap + bank XOR swizzle). q~ pre-scaled by LOG2E.
__global__ __launch_bounds__(256) void prep1_kernel(
    const _Float16* __restrict__ qkvh, const float* __restrict__ pos,
    _Float16* __restrict__ qt, _Float16* __restrict__ kt,
    _Float16* __restrict__ vt2)
{
    __shared__ float tile[64][65];
    int head = blockIdx.x, tau = blockIdx.y;
    int s0 = tau * 64;
    int b = head >> 4, rh = head & 15;
    int lane = threadIdx.x & 63, w = threadIdx.x >> 6;

#pragma unroll
    for (int si = w; si < 64; si += 4)
        tile[si][lane] =
            (float)qkvh[(size_t)(b * S_ + s0 + si) * NQKV + rh * 192 + 128 + lane];
    __syncthreads();
    {
        int P = lane;
        int op = P >> 3;
        int hi = (P >> 2) & 1, lo = P & 3;
#pragma unroll
        for (int d = w; d < 64; d += 4) {
            int ol = op ^ (d & 7);
            int key = 32 * (ol >> 2) + 16 * hi + 4 * (ol & 3) + lo;
            vt2[(((size_t)head * 32 + tau) * 64 + d) * 64 + P] = (_Float16)tile[key][d];
        }
    }

    for (int i = 0; i < 16; ++i) {
        int s = s0 + w * 16 + i;
        int bs = b * S_ + s;
        const _Float16* base = qkvh + (size_t)bs * NQKV + rh * 192;
        float qv = (float)base[lane];
        float kv = (float)base[64 + lane];

        float ss = kv * kv;
#pragma unroll
        for (int off = 32; off > 0; off >>= 1) ss += __shfl_xor(ss, off);
        kv *= rsqrtf(ss);

        int j = lane & 31;
        float sn = pos[(size_t)bs * 64 + j];
        float cs = pos[(size_t)bs * 64 + 32 + j];
        float qp = __shfl_xor(qv, 32);
        float kp = __shfl_xor(kv, 32);
        float qo, ko;
        if (lane < 32) { qo = qv * cs - qp * sn; ko = kv * cs - kp * sn; }
        else           { qo = qp * sn + qv * cs; ko = kp * sn + kv * cs; }

        size_t oidx = ((size_t)head * S_ + s) * 64 + lane;
        qt[oidx] = (_Float16)(qo * LOG2E);   // fold log2(e) into q~
        kt[oidx] = (_Float16)ko;
    }
}

// ------- transposed MFMA flash attention, key-split x2, K/V dbuf -----------
// grid (32 heads, 16 q-tiles of 128, 2 key-splits), block 256 = 4 waves;
// wave w owns 32 queries as 2 q-groups of 16. Split ks handles keys
// [ks*1024, ks*1024+1024) = 16 tiles of 64. Static-max softmax => partials
// (unnormalized O in f16, l in f32) are exactly additive across splits.
__global__ __launch_bounds__(256) void attn_mfma_kernel(
    const _Float16* __restrict__ qt, const _Float16* __restrict__ kt,
    const _Float16* __restrict__ vt2,
    _Float16* __restrict__ opart, float* __restrict__ lpart)
{
    __shared__ _Float16 Kls[2][4096];
    __shared__ _Float16 Vls[2][4096];

    int head = blockIdx.x, q0 = blockIdx.y * 128, ks = blockIdx.z;
    int b = head >> 4, rh = head & 15;
    int tid = threadIdx.x, lane = tid & 63, w = tid >> 6;
    int g = lane >> 4, c = lane & 15;

    // Q B-frags + static softmax bound mL = |q~| (log2 units) per q-group
    half8 qf[2][2];
    float mL[2], l_s[2] = {0.f, 0.f};
#pragma unroll
    for (int qg = 0; qg < 2; ++qg) {
        const _Float16* qp =
            qt + ((size_t)head * S_ + q0 + w * 32 + qg * 16 + c) * 64 + 8 * g;
        qf[qg][0] = *(const half8*)qp;
        qf[qg][1] = *(const half8*)(qp + 32);
        float qq = 0.f;
#pragma unroll
        for (int i = 0; i < 8; ++i) {
            float a = (float)qf[qg][0][i], b2 = (float)qf[qg][1][i];
            qq += a * a + b2 * b2;
        }
        qq += __shfl_xor(qq, 16);
        qq += __shfl_xor(qq, 32);
        mL[qg] = sqrtf(qq);       // s_log2 <= |q~|*|k^| = mL  (k^ unit norm)
    }

    floatx4 o_acc[2][4] = {};

    // staging geometry (per wave: K chunks {2w,2w+1}, V chunks {2w,2w+1}).
    const _Float16* kg[2]; const _Float16* vg[2];
    int loff[2];
#pragma unroll
    for (int i2 = 0; i2 < 2; ++i2) {
        int ch = 2 * w + i2;
        int krow = ch * 8 + (lane >> 3);
        int koct = (lane & 7) ^ (lane >> 3);
        kg[i2] = kt + ((size_t)head * S_ + krow) * 64 + koct * 8;
        vg[i2] = vt2 + ((size_t)head * 32) * 4096 + ch * 512 + lane * 8;
        loff[i2] = ch * 512;
    }

    int co = c & 7;   // XOR swizzle term for frag reads
    int jbase = ks << 4;   // global tile index base for this split

    // prologue: stage tile jbase into buffer 0
#pragma unroll
    for (int i2 = 0; i2 < 2; ++i2) {
        gl_lds16(kg[i2] + (size_t)jbase * 4096, &Kls[0][loff[i2]]);
        gl_lds16(vg[i2] + (size_t)jbase * 4096, &Vls[0][loff[i2]]);
    }

    for (int jt = 0; jt < 16; ++jt) {
        int cur = jt & 1;
        __syncthreads();       // buf[cur] staged; buf[cur^1] free
        if (jt + 1 < 16) {
            size_t joff = (size_t)(jbase + jt + 1) * 4096;
#pragma unroll
            for (int i2 = 0; i2 < 2; ++i2) {
                gl_lds16(kg[i2] + joff, &Kls[cur ^ 1][loff[i2]]);
                gl_lds16(vg[i2] + joff, &Vls[cur ^ 1][loff[i2]]);
            }
        }
        const _Float16* Kbuf = Kls[cur];
        const _Float16* Vbuf = Vls[cur];

        // ---- K fragments once, shared by both q-groups ----
        half8 kfr[8];
#pragma unroll
        for (int t = 0; t < 4; ++t) {
            const _Float16* krow = Kbuf + (16 * t + c) * 64;
            kfr[2 * t]     = *(const half8*)(krow + ((g) ^ co) * 8);
            kfr[2 * t + 1] = *(const half8*)(krow + ((4 + g) ^ co) * 8);
        }

        union { half8 v; fp16x2 h2[4]; } pf[2][2];
#pragma unroll
        for (int qg = 0; qg < 2; ++qg) {
            floatx4 sacc[4];
#pragma unroll
            for (int t = 0; t < 4; ++t) {
                floatx4 z = {};
                z = __builtin_amdgcn_mfma_f32_16x16x32_f16(
                    kfr[2 * t], qf[qg][0], z, 0, 0, 0);
                z = __builtin_amdgcn_mfma_f32_16x16x32_f16(
                    kfr[2 * t + 1], qf[qg][1], z, 0, 0, 0);
                sacc[t] = z;
            }
            float mLq = mL[qg], ps = 0.f;
#pragma unroll
            for (int t = 0; t < 4; ++t)
#pragma unroll
                for (int r = 0; r < 4; ++r) {
                    float p = EXP2(sacc[t][r] - mLq);
                    sacc[t][r] = p;
                    ps += p;
                }
            l_s[qg] += ps;
            pf[qg][0].h2[0] = __builtin_amdgcn_cvt_pkrtz(sacc[0][0], sacc[0][1]);
            pf[qg][0].h2[1] = __builtin_amdgcn_cvt_pkrtz(sacc[0][2], sacc[0][3]);
            pf[qg][0].h2[2] = __builtin_amdgcn_cvt_pkrtz(sacc[1][0], sacc[1][1]);
            pf[qg][0].h2[3] = __builtin_amdgcn_cvt_pkrtz(sacc[1][2], sacc[1][3]);
            pf[qg][1].h2[0] = __builtin_amdgcn_cvt_pkrtz(sacc[2][0], sacc[2][1]);
            pf[qg][1].h2[1] = __builtin_amdgcn_cvt_pkrtz(sacc[2][2], sacc[2][3]);
            pf[qg][1].h2[2] = __builtin_amdgcn_cvt_pkrtz(sacc[3][0], sacc[3][1]);
            pf[qg][1].h2[3] = __builtin_amdgcn_cvt_pkrtz(sacc[3][2], sacc[3][3]);
        }

        // ---- V fragments once, shared; O^T += V^T @ P^T ----
#pragma unroll
        for (int t = 0; t < 4; ++t) {
            const _Float16* vrow = Vbuf + (16 * t + c) * 64;
            half8 v0 = *(const half8*)(vrow + ((g) ^ co) * 8);
            half8 v1 = *(const half8*)(vrow + ((4 + g) ^ co) * 8);
#pragma unroll
            for (int qg = 0; qg < 2; ++qg) {
                o_acc[qg][t] = __builtin_amdgcn_mfma_f32_16x16x32_f16(
                    v0, pf[qg][0].v, o_acc[qg][t], 0, 0, 0);
                o_acc[qg][t] = __builtin_amdgcn_mfma_f32_16x16x32_f16(
                    v1, pf[qg][1].v, o_acc[qg][t], 0, 0, 0);
            }
        }
    }

    // ---- epilogue: write UNNORMALIZED O (f16) + l partial (f32) ----
#pragma unroll
    for (int qg = 0; qg < 2; ++qg) {
        float lt = l_s[qg];
        lt += __shfl_xor(lt, 16);
        lt += __shfl_xor(lt, 32);
        int q = q0 + w * 32 + qg * 16 + c;
        if (lane < 16)    // one lane per query (g==0)
            lpart[((size_t)ks * 32 + head) * S_ + q] = lt;
        size_t rowbase =
            ((size_t)ks * BS_ + (size_t)(b * S_ + q)) * 1024 + rh * 64;
#pragma unroll
        for (int t = 0; t < 4; ++t) {
            union { half4 v; fp16x2 h2[2]; } e;
            e.h2[0] = __builtin_amdgcn_cvt_pkrtz(o_acc[qg][t][0], o_acc[qg][t][1]);
            e.h2[1] = __builtin_amdgcn_cvt_pkrtz(o_acc[qg][t][2], o_acc[qg][t][3]);
            *(half4*)(opart + rowbase + 16 * t + 4 * g) = e.v;
        }
    }
}

// --------- merge key-split partials: ctx = (O0+O1)/(l0+l1) -----------------
// grid 2048 x 256: each thread handles one (row, col-octet) = 8 halves.
__global__ __launch_bounds__(256) void merge_kernel(
    const _Float16* __restrict__ opart, const float* __restrict__ lpart,
    _Float16* __restrict__ ctx)
{
    int idx = blockIdx.x * 256 + threadIdx.x;
    int row = idx >> 7;            // bs row
    int col = (idx & 127) * 8;
    int b = row >> 11, s = row & 2047;
    int head = b * 16 + (col >> 6);
    float l0 = lpart[(size_t)head * S_ + s];
    float l1 = lpart[(size_t)(32 + head) * S_ + s];
    float inv = 1.f / (l0 + l1);
    size_t off = (size_t)row * 1024 + col;
    half8 a = *(const half8*)(opart + off);
    half8 b8 = *(const half8*)(opart + (size_t)BS_ * 1024 + off);
    union { half8 v; fp16x2 h2[4]; } e;
#pragma unroll
    for (int i = 0; i < 4; ++i)
        e.h2[i] = __builtin_amdgcn_cvt_pkrtz(
            ((float)a[2 * i]     + (float)b8[2 * i])     * inv,
            ((float)a[2 * i + 1] + (float)b8[2 * i + 1]) * inv);
    *(half8*)(ctx + off) = e.v;
}

// --------------------- LayerNorm in place on y[4096][1024] -----------------
__global__ __launch_bounds__(256) void ln_kernel(
    float* __restrict__ y, const float* __restrict__ g, const float* __restrict__ bb)
{
    int row = blockIdx.x, tid = threadIdx.x;
    float* p = y + (size_t)row * 1024;
    float4 v = ((const float4*)p)[tid];
    float sum = v.x + v.y + v.z + v.w;
    float sq  = v.x*v.x + v.y*v.y + v.z*v.z + v.w*v.w;
#pragma unroll
    for (int off = 32; off > 0; off >>= 1) {
        sum += __shfl_xor(sum, off);
        sq  += __shfl_xor(sq,  off);
    }
    __shared__ float rs[4], rq[4];
    int w = tid >> 6;
    if ((tid & 63) == 0) { rs[w] = sum; rq[w] = sq; }
    __syncthreads();
    sum = rs[0] + rs[1] + rs[2] + rs[3];
    sq  = rq[0] + rq[1] + rq[2] + rq[3];
    float mean = sum * (1.f / 1024.f);
    float var  = sq * (1.f / 1024.f) - mean * mean;
    float inv  = rsqrtf(var + 1e-5f);
    float4 gv = ((const float4*)g)[tid];
    float4 bv = ((const float4*)bb)[tid];
    v.x = (v.x - mean) * inv * gv.x + bv.x;
    v.y = (v.y - mean) * inv * gv.y + bv.y;
    v.z = (v.z - mean) * inv * gv.z + bv.z;
    v.w = (v.w - mean) * inv * gv.w + bv.w;
    ((float4*)p)[tid] = v;
}

// ---------------------------------------------------------------------------
extern "C" void kernel_launch(void* const* d_in, const int* in_sizes, int n_in,
                              void* d_out, int out_size, void* d_ws, size_t ws_size,
                              hipStream_t stream)
{
    const float* x     = (const float*)d_in[0];
    const float* pos   = (const float*)d_in[1];
    const float* W_qkv = (const float*)d_in[2];
    const float* b_qkv = (const float*)d_in[3];
    const float* W_out = (const float*)d_in[4];
    const float* b_out = (const float*)d_in[5];
    const float* ln_g  = (const float*)d_in[6];
    const float* ln_b  = (const float*)d_in[7];
    float* out = (float*)d_out;

    // workspace layout (~90 MB)
    char* ws = (char*)d_ws;
    _Float16* x_h    = (_Float16*)(ws);                       //  8 MB
    _Float16* wqkv_t = (_Float16*)(ws + ((size_t)8  << 20));  //  6 MB
    _Float16* wout_t = (_Float16*)(ws + ((size_t)14 << 20));  //  2 MB
    _Float16* qkvh   = (_Float16*)(ws + ((size_t)16 << 20));  // 24 MB (f16)
    _Float16* qt_h   = (_Float16*)(ws + ((size_t)40 << 20));  //  8 MB
    _Float16* kt_h   = (_Float16*)(ws + ((size_t)48 << 20));  //  8 MB
    _Float16* vt2_h  = (_Float16*)(ws + ((size_t)56 << 20));  //  8 MB
    _Float16* ctx_h  = (_Float16*)(ws + ((size_t)64 << 20));  //  8 MB
    _Float16* opart  = (_Float16*)(ws + ((size_t)72 << 20));  // 16 MB (2 splits)
    float*    lpart  = (float*)   (ws + ((size_t)88 << 20));  // 0.5 MB

    // 1) fused cast + weight transposes
    prep0_kernel<<<8192, 256, 0, stream>>>(x, x_h, W_qkv, wqkv_t, W_out, wout_t);

    // 2) qkv (f16) = x @ W_qkv + b_qkv
    gemm_f16_mfma<<<dim3(NQKV / 128, BS_ / 128), 256, 0, stream>>>(
        x_h, wqkv_t, b_qkv, qkvh, BS_, NQKV, H_);

    // 3) fused k-norm + RoPE + V-image
    prep1_kernel<<<dim3(32, 32), 256, 0, stream>>>(qkvh, pos, qt_h, kt_h, vt2_h);

    // 4) MFMA flash attention, key-split x2 -> partials
    attn_mfma_kernel<<<dim3(32, 16, 2), 256, 0, stream>>>(
        qt_h, kt_h, vt2_h, opart, lpart);

    // 5) merge partials -> ctx f16
    merge_kernel<<<2048, 256, 0, stream>>>(opart, lpart, ctx_h);

    // 6) out (fp32) = x + ctx @ W_out + b_out   (64x64 tiles, 4 blocks/CU)
    gemm64_f16_mfma<<<dim3(H_ / 64, BS_ / 64), 256, 0, stream>>>(
        ctx_h, wout_t, b_out, x, out, BS_, H_, H_);

    // 7) LayerNorm in place
    ln_kernel<<<BS_, 256, 0, stream>>>(out, ln_g, ln_b);
}